// Round 1
// baseline (8009.630 us; speedup 1.0000x reference)
//
#include <hip/hip_runtime.h>
#include <math.h>

#define NWG 256
#define NT  512

namespace {
constexpr int T_ = 32, B_ = 32, H_ = 512, S_ = 512;
constexpr int BH = B_ * H_;       // 16384
}

// Grid-barrier flags: module-scope (zero-initialized at load), monotonic across
// launches/replays so poisoned d_ws can never corrupt sync state.
__device__ unsigned g_flags[NWG] = {};

static __device__ __forceinline__ float sigm(float x) { return 1.0f / (1.0f + expf(-x)); }
static __device__ __forceinline__ float dot4(float4 a, float4 b) {
  return a.x * b.x + a.y * b.y + a.z * b.z + a.w * b.w;
}

// All-to-all flag barrier. Every WG writes its own flag (release, agent scope),
// wave 0 of each WG polls all flags, then an agent acquire fence.
static __device__ __forceinline__ void grid_barrier(unsigned target) {
  __syncthreads();
  if (threadIdx.x == 0) {
    __hip_atomic_store(&g_flags[blockIdx.x], target, __ATOMIC_RELEASE,
                       __HIP_MEMORY_SCOPE_AGENT);
  }
  if (threadIdx.x < 64) {
    for (int i = threadIdx.x; i < NWG; i += 64) {
      while (__hip_atomic_load(&g_flags[i], __ATOMIC_RELAXED,
                               __HIP_MEMORY_SCOPE_AGENT) < target) {
        __builtin_amdgcn_s_sleep(1);
      }
    }
  }
  __builtin_amdgcn_fence(__ATOMIC_ACQUIRE, "agent");
  __syncthreads();
}

// ---- LSTM cell stage: gates = x@Wih^T + h@Whh^T + (bi+bh); update h,c ----
// WG g owns 2 output columns (j = g*2 + jj). threads: (b:32, jj:2, ks:8).
// K = 1024 total (x part 512 | h part 512), each thread does a 128-slice for 4 gate rows.
static __device__ __forceinline__ void stage_lstm(
    const float* __restrict__ x, const float* __restrict__ h,
    const float* __restrict__ c, const float* __restrict__ Wih,
    const float* __restrict__ Whh, const float* __restrict__ bi,
    const float* __restrict__ bh, float* __restrict__ hq, float* __restrict__ cq,
    int g, int tid, float* smem)
{
  const int b = tid & 31, jj = (tid >> 5) & 1, ks = tid >> 6;
  const int j = g * 2 + jj;
  const float* src = (ks < 4) ? (x + b * H_ + ks * 128)
                              : (h + b * H_ + (ks - 4) * 128);
  const float* wb = (ks < 4) ? Wih : Whh;
  const int koff = (ks & 3) * 128;
  const float* w0 = wb + (size_t)(0 * H_ + j) * H_ + koff;
  const float* w1 = wb + (size_t)(1 * H_ + j) * H_ + koff;
  const float* w2 = wb + (size_t)(2 * H_ + j) * H_ + koff;
  const float* w3 = wb + (size_t)(3 * H_ + j) * H_ + koff;
  float a0 = 0.f, a1 = 0.f, a2 = 0.f, a3 = 0.f;
#pragma unroll 4
  for (int k = 0; k < 128; k += 4) {
    float4 x4 = *(const float4*)(src + k);
    a0 += dot4(x4, *(const float4*)(w0 + k));
    a1 += dot4(x4, *(const float4*)(w1 + k));
    a2 += dot4(x4, *(const float4*)(w2 + k));
    a3 += dot4(x4, *(const float4*)(w3 + k));
  }
  const int oidx = jj * 32 + b;           // 0..63
  smem[(oidx * 4 + 0) * 8 + ks] = a0;
  smem[(oidx * 4 + 1) * 8 + ks] = a1;
  smem[(oidx * 4 + 2) * 8 + ks] = a2;
  smem[(oidx * 4 + 3) * 8 + ks] = a3;
  __syncthreads();
  if (tid < 64) {
    const int bb = tid & 31, j2 = tid >> 5;
    const int jo = g * 2 + j2;
    const int base = tid * 32;
    float gi = 0.f, gf = 0.f, gg = 0.f, go = 0.f;
#pragma unroll
    for (int k = 0; k < 8; ++k) {
      gi += smem[base + k];
      gf += smem[base + 8 + k];
      gg += smem[base + 16 + k];
      go += smem[base + 24 + k];
    }
    gi += bi[0 * H_ + jo] + bh[0 * H_ + jo];
    gf += bi[1 * H_ + jo] + bh[1 * H_ + jo];
    gg += bi[2 * H_ + jo] + bh[2 * H_ + jo];
    go += bi[3 * H_ + jo] + bh[3 * H_ + jo];
    const float cp = c[bb * H_ + jo];
    const float cn = sigm(gf) * cp + sigm(gi) * tanhf(gg);
    const float hn = sigm(go) * tanhf(cn);
    cq[bb * H_ + jo] = cn;
    hq[bb * H_ + jo] = hn;
  }
}

// ---- small GEMV stage: outv = x @ Wi^T + bi  (H x H) ----
static __device__ __forceinline__ void stage_gemv(
    const float* __restrict__ x, const float* __restrict__ Wi,
    const float* __restrict__ bi, float* __restrict__ outv,
    int g, int tid, float* smem)
{
  const int b = tid & 31, jj = (tid >> 5) & 1, ks = tid >> 6;
  const int j = g * 2 + jj;
  const float* src = x + b * H_ + ks * 64;
  const float* w = Wi + (size_t)j * H_ + ks * 64;
  float acc = 0.f;
#pragma unroll 4
  for (int k = 0; k < 64; k += 4)
    acc += dot4(*(const float4*)(src + k), *(const float4*)(w + k));
  smem[(jj * 32 + b) * 8 + ks] = acc;
  __syncthreads();
  if (tid < 64) {
    const int bb = tid & 31, j2 = tid >> 5;
    const int jo = g * 2 + j2;
    float s = 0.f;
#pragma unroll
    for (int k = 0; k < 8; ++k) s += smem[tid * 8 + k];
    outv[bb * H_ + jo] = s + bi[jo];
  }
}

// ---- conv attention pass: single sweep, sigmoid weights, partial ct per (b, s-chunk) ----
static __device__ __forceinline__ void stage_convpass(
    const float* __restrict__ cc, const float* __restrict__ gc,
    float* __restrict__ part, int g, int tid, float* smem)
{
  const int b = g >> 3, sc = g & 7;
  const int w = tid >> 6, lane = tid & 63;
  const float* gbase = gc + b * H_ + lane * 8;
  const float4 g0 = *(const float4*)(gbase);
  const float4 g1 = *(const float4*)(gbase + 4);
  float4 a0 = {0, 0, 0, 0}, a1 = {0, 0, 0, 0};
  for (int i = 0; i < 8; ++i) {
    const int s = sc * 64 + w * 8 + i;
    const float* xr = cc + ((size_t)b * S_ + s) * H_ + lane * 8;
    const float4 x0 = *(const float4*)(xr);
    const float4 x1 = *(const float4*)(xr + 4);
    float p = dot4(x0, g0) + dot4(x1, g1);
#pragma unroll
    for (int off = 32; off >= 1; off >>= 1) p += __shfl_xor(p, off, 64);
    const float wt = 1.0f / (1.0f + expf(-p));
    a0.x += wt * x0.x; a0.y += wt * x0.y; a0.z += wt * x0.z; a0.w += wt * x0.w;
    a1.x += wt * x1.x; a1.y += wt * x1.y; a1.z += wt * x1.z; a1.w += wt * x1.w;
  }
  float* wbuf = smem + w * 512 + lane * 8;
  *(float4*)(wbuf) = a0;
  *(float4*)(wbuf + 4) = a1;
  __syncthreads();
  float sacc = 0.f;
#pragma unroll
  for (int ww = 0; ww < 8; ++ww) sacc += smem[ww * 512 + tid];
  part[((size_t)b * 8 + sc) * H_ + tid] = sacc;
}

// ---- softmax attention pass: online softmax, partial (m, l, acc) per (b, s-chunk) ----
static __device__ __forceinline__ void stage_attpass(
    const float* __restrict__ cx, const float* __restrict__ ga,
    float* __restrict__ part, float* __restrict__ pml,
    int g, int tid, float* smem)
{
  const int b = g >> 3, sc = g & 7;
  const int w = tid >> 6, lane = tid & 63;
  const float* gbase = ga + b * H_ + lane * 8;
  const float4 g0 = *(const float4*)(gbase);
  const float4 g1 = *(const float4*)(gbase + 4);
  float4 a0 = {0, 0, 0, 0}, a1 = {0, 0, 0, 0};
  float m = -INFINITY, l = 0.f;
  for (int i = 0; i < 8; ++i) {
    const int s = sc * 64 + w * 8 + i;
    const float* xr = cx + ((size_t)b * S_ + s) * H_ + lane * 8;
    const float4 x0 = *(const float4*)(xr);
    const float4 x1 = *(const float4*)(xr + 4);
    float p = dot4(x0, g0) + dot4(x1, g1);
#pragma unroll
    for (int off = 32; off >= 1; off >>= 1) p += __shfl_xor(p, off, 64);
    const float m2 = fmaxf(m, p);
    const float f = expf(m - m2);     // first iter: exp(-inf)=0
    const float e = expf(p - m2);
    l = l * f + e;
    a0.x = a0.x * f + e * x0.x; a0.y = a0.y * f + e * x0.y;
    a0.z = a0.z * f + e * x0.z; a0.w = a0.w * f + e * x0.w;
    a1.x = a1.x * f + e * x1.x; a1.y = a1.y * f + e * x1.y;
    a1.z = a1.z * f + e * x1.z; a1.w = a1.w * f + e * x1.w;
    m = m2;
  }
  float* wbuf = smem + w * 512 + lane * 8;
  *(float4*)(wbuf) = a0;
  *(float4*)(wbuf + 4) = a1;
  if (lane == 0) { smem[4096 + w] = m; smem[4104 + w] = l; }
  __syncthreads();
  float M = smem[4096];
#pragma unroll
  for (int ww = 1; ww < 8; ++ww) M = fmaxf(M, smem[4096 + ww]);
  float fac[8], L = 0.f;
#pragma unroll
  for (int ww = 0; ww < 8; ++ww) {
    fac[ww] = expf(smem[4096 + ww] - M);
    L += fac[ww] * smem[4104 + ww];
  }
  float sacc = 0.f;
#pragma unroll
  for (int ww = 0; ww < 8; ++ww) sacc += fac[ww] * smem[ww * 512 + tid];
  part[((size_t)b * 8 + sc) * H_ + tid] = sacc;
  if (tid == 0) {
    pml[(b * 8 + sc) * 2] = M;
    pml[(b * 8 + sc) * 2 + 1] = L;
  }
}

// ---- output GEMM helper: res[j] = ct(smem[0..511]) . Wo[j][0:512] + xg . Wo[j][512:1024] ----
static __device__ __forceinline__ float out_gemm(
    const float* smem, const float* __restrict__ xg,
    const float* __restrict__ Wo, int jc, float* red, int tid)
{
  const int jl = tid & 63, ks = tid >> 6;
  const int j = jc * 64 + jl;
  const float* wr = Wo + (size_t)j * (2 * H_) + ks * 128;
  float acc = 0.f;
  if (ks < 4) {
    const float* s1 = smem + ks * 128;
#pragma unroll 4
    for (int k = 0; k < 128; k += 4)
      acc += dot4(*(const float4*)(s1 + k), *(const float4*)(wr + k));
  } else {
    const float* s2 = xg + (ks - 4) * 128;
#pragma unroll 4
    for (int k = 0; k < 128; k += 4)
      acc += dot4(*(const float4*)(s2 + k), *(const float4*)(wr + k));
  }
  red[ks * 64 + jl] = acc;
  __syncthreads();
  float s = 0.f;
  if (tid < 64) {
#pragma unroll
    for (int c = 0; c < 8; ++c) s += red[c * 64 + tid];
  }
  return s;
}

// ---- out_conv = tanh([ct_c, h1n] @ Wo_conv^T + bo_conv) ----
static __device__ __forceinline__ void stage_outconv(
    const float* __restrict__ part, const float* __restrict__ h1n,
    const float* __restrict__ Wo, const float* __restrict__ bo,
    float* __restrict__ ocv, int g, int tid, float* smem)
{
  const int b = g >> 3, jc = g & 7;
  float s0 = 0.f;
#pragma unroll
  for (int c = 0; c < 8; ++c) s0 += part[((size_t)b * 8 + c) * H_ + tid];
  smem[tid] = s0;
  __syncthreads();
  const float s = out_gemm(smem, h1n + b * H_, Wo, jc, smem + 512, tid);
  if (tid < 64) {
    const int jo = jc * 64 + tid;
    ocv[b * H_ + jo] = tanhf(s + bo[jo]);
  }
}

// ---- out = tanh([ct, out_conv] @ Wo_att^T + bo_att) + out_conv ----
static __device__ __forceinline__ void stage_outatt(
    const float* __restrict__ part, const float* __restrict__ pml,
    const float* __restrict__ ocv, const float* __restrict__ Wo,
    const float* __restrict__ bo, float* __restrict__ outp,
    int g, int tid, float* smem)
{
  const int b = g >> 3, jc = g & 7;
  float M = pml[(b * 8 + 0) * 2];
#pragma unroll
  for (int c = 1; c < 8; ++c) M = fmaxf(M, pml[(b * 8 + c) * 2]);
  float fac[8], L = 0.f;
#pragma unroll
  for (int c = 0; c < 8; ++c) {
    fac[c] = expf(pml[(b * 8 + c) * 2] - M);
    L += fac[c] * pml[(b * 8 + c) * 2 + 1];
  }
  const float inv = 1.0f / L;
  float s0 = 0.f;
#pragma unroll
  for (int c = 0; c < 8; ++c) s0 += fac[c] * part[((size_t)b * 8 + c) * H_ + tid];
  smem[tid] = s0 * inv;
  __syncthreads();
  const float s = out_gemm(smem, ocv + b * H_, Wo, jc, smem + 512, tid);
  if (tid < 64) {
    const int jo = jc * 64 + tid;
    outp[b * H_ + jo] = tanhf(s + bo[jo]) + ocv[b * H_ + jo];
  }
}

__global__ __launch_bounds__(NT)
void rnn_all(const int* __restrict__ inputs, const float* __restrict__ h0in,
             const float* __restrict__ c0in, const float* __restrict__ ctx,
             const float* __restrict__ ctxc, const float* __restrict__ emb,
             const float* __restrict__ W_ih, const float* __restrict__ W_hh,
             const float* __restrict__ b_ih, const float* __restrict__ b_hh,
             const float* __restrict__ Wi_att, const float* __restrict__ bi_att,
             const float* __restrict__ Wo_att, const float* __restrict__ bo_att,
             const float* __restrict__ Wi_conv, const float* __restrict__ bi_conv,
             const float* __restrict__ Wo_conv, const float* __restrict__ bo_conv,
             float* __restrict__ out, float* __restrict__ ws)
{
  const int g = blockIdx.x;
  const int tid = threadIdx.x;

  // workspace layout (floats)
  float* EMBS = ws;                    // [T*B][H]           524288
  float* H0   = EMBS + (size_t)T_ * BH; // [2][BH]
  float* C0   = H0 + 2 * BH;
  float* H1   = C0 + 2 * BH;
  float* C1   = H1 + 2 * BH;
  float* GC   = C1 + 2 * BH;           // gamma_conv [BH]
  float* GA   = GC + BH;               // gamma_att  [BH]
  float* OCV  = GA + BH;               // out_conv   [BH]
  float* PART = OCV + BH;              // [B][8][H]          131072
  float* PML  = PART + (size_t)B_ * 8 * H_; // [B][8][2]     512

  __shared__ float smem[4224];

  unsigned bar = __hip_atomic_load(&g_flags[g], __ATOMIC_RELAXED,
                                   __HIP_MEMORY_SCOPE_AGENT);

  // ---- P0: init recurrent state (ping 0) + gather embeddings ----
  {
    const int gid = g * NT + tid;
    if (gid < BH) {
      H0[gid] = h0in[gid];
      H1[gid] = h0in[BH + gid];
      C0[gid] = c0in[gid];
      C1[gid] = c0in[BH + gid];
    }
    for (int r = 0; r < 4; ++r) {
      const int tb = g * 4 + r;
      const int row = inputs[tb];
      EMBS[(size_t)tb * H_ + tid] = emb[(size_t)row * H_ + tid];
    }
  }
  grid_barrier(++bar);

  const float* Wih0 = W_ih;
  const float* Whh0 = W_hh;
  const float* Wih1 = W_ih + (size_t)4 * H_ * H_;
  const float* Whh1 = W_hh + (size_t)4 * H_ * H_;

  for (int t = 0; t < T_; ++t) {
    const int p = t & 1, q = p ^ 1;
    const float* h0p = H0 + p * BH; float* h0q = H0 + q * BH;
    const float* c0p = C0 + p * BH; float* c0q = C0 + q * BH;
    const float* h1p = H1 + p * BH; float* h1q = H1 + q * BH;
    const float* c1p = C1 + p * BH; float* c1q = C1 + q * BH;

    // S1: layer-0 LSTM
    stage_lstm(EMBS + (size_t)t * BH, h0p, c0p, Wih0, Whh0,
               b_ih, b_hh, h0q, c0q, g, tid, smem);
    grid_barrier(++bar);
    // S2: layer-1 LSTM (x = new h0)
    stage_lstm(h0q, h1p, c1p, Wih1, Whh1,
               b_ih + 4 * H_, b_hh + 4 * H_, h1q, c1q, g, tid, smem);
    grid_barrier(++bar);
    // S3: gamma_conv = h1n @ Wi_conv^T + bi_conv
    stage_gemv(h1q, Wi_conv, bi_conv, GC, g, tid, smem);
    grid_barrier(++bar);
    // S4: sigmoid-gated sweep over contexts_conv -> partial ct_c
    stage_convpass(ctxc, GC, PART, g, tid, smem);
    grid_barrier(++bar);
    // S5: out_conv
    stage_outconv(PART, h1q, Wo_conv, bo_conv, OCV, g, tid, smem);
    grid_barrier(++bar);
    // S6: gamma_att = out_conv @ Wi_att^T + bi_att
    stage_gemv(OCV, Wi_att, bi_att, GA, g, tid, smem);
    grid_barrier(++bar);
    // S7: online-softmax sweep over contexts -> partial (m,l,ct)
    stage_attpass(ctx, GA, PART, PML, g, tid, smem);
    grid_barrier(++bar);
    // S8: out[t]
    stage_outatt(PART, PML, OCV, Wo_att, bo_att, out + (size_t)t * BH,
                 g, tid, smem);
    grid_barrier(++bar);
  }

  // final h/c: t=31 wrote ping 0. layout: outputs[T*BH] | hf[2*BH] | cf[2*BH]
  {
    const int gid = g * NT + tid;
    if (gid < BH) {
      out[(size_t)T_ * BH + gid]          = H0[gid];
      out[(size_t)T_ * BH + BH + gid]     = H1[gid];
      out[(size_t)T_ * BH + 2 * BH + gid] = C0[gid];
      out[(size_t)T_ * BH + 3 * BH + gid] = C1[gid];
    }
  }
}

extern "C" void kernel_launch(void* const* d_in, const int* in_sizes, int n_in,
                              void* d_out, int out_size, void* d_ws, size_t ws_size,
                              hipStream_t stream) {
  rnn_all<<<dim3(NWG), dim3(NT), 0, stream>>>(
      (const int*)d_in[0],   (const float*)d_in[1],  (const float*)d_in[2],
      (const float*)d_in[3], (const float*)d_in[4],  (const float*)d_in[5],
      (const float*)d_in[6], (const float*)d_in[7],  (const float*)d_in[8],
      (const float*)d_in[9], (const float*)d_in[10], (const float*)d_in[11],
      (const float*)d_in[12],(const float*)d_in[13], (const float*)d_in[14],
      (const float*)d_in[15],(const float*)d_in[16], (const float*)d_in[17],
      (float*)d_out, (float*)d_ws);
}

// Round 4
// 2101.751 us; speedup vs baseline: 3.8109x; 3.8109x over previous
//
#include <hip/hip_runtime.h>
#include <math.h>

#define NWG 256
#define NT  512

namespace {
constexpr int T_ = 32, B_ = 32, H_ = 512, S_ = 512;
constexpr int BH = B_ * H_;   // 16384
}

// Monotonic barrier state (module scope: zero-init at load, survives replays,
// immune to the 0xAA workspace poison).
__device__ unsigned g_arrive[NWG] = {};
__device__ unsigned g_go = 0;

static __device__ __forceinline__ float sigm(float x) { return 1.0f / (1.0f + expf(-x)); }
static __device__ __forceinline__ float dot4(float4 a, float4 b) {
  return a.x * b.x + a.y * b.y + a.z * b.z + a.w * b.w;
}
static __device__ __forceinline__ void fma4(float4& a, float s, float4 x) {
  a.x += s * x.x; a.y += s * x.y; a.z += s * x.z; a.w += s * x.w;
}
static __device__ __forceinline__ void scale_fma4(float4& a, float f, float e, float4 x) {
  a.x = a.x * f + e * x.x; a.y = a.y * f + e * x.y;
  a.z = a.z * f + e * x.z; a.w = a.w * f + e * x.w;
}

// Central two-level barrier. Release: entry __syncthreads() + tid0 RELEASE
// store (agent scope). Acquire: agent ACQUIRE fence by ALL threads after the
// final __syncthreads().
static __device__ __forceinline__ void grid_barrier(unsigned target) {
  __syncthreads();
  if (threadIdx.x == 0)
    __hip_atomic_store(&g_arrive[blockIdx.x], target, __ATOMIC_RELEASE,
                       __HIP_MEMORY_SCOPE_AGENT);
  if (blockIdx.x == 0) {
    if (threadIdx.x < 64) {
      for (int i = threadIdx.x; i < NWG; i += 64)
        while (__hip_atomic_load(&g_arrive[i], __ATOMIC_RELAXED,
                                 __HIP_MEMORY_SCOPE_AGENT) < target)
          __builtin_amdgcn_s_sleep(2);
    }
    __syncthreads();
    __builtin_amdgcn_fence(__ATOMIC_ACQUIRE, "agent");   // transitivity for relay
    if (threadIdx.x == 0)
      __hip_atomic_store(&g_go, target, __ATOMIC_RELEASE,
                         __HIP_MEMORY_SCOPE_AGENT);
  }
  if (threadIdx.x == 0)
    while (__hip_atomic_load(&g_go, __ATOMIC_RELAXED,
                             __HIP_MEMORY_SCOPE_AGENT) < target)
      __builtin_amdgcn_s_sleep(2);
  __syncthreads();
  __builtin_amdgcn_fence(__ATOMIC_ACQUIRE, "agent");  // AFTER sync: all threads
}

__global__ __launch_bounds__(NT)
void rnn_all(const int* __restrict__ inputs, const float* __restrict__ h0in,
             const float* __restrict__ c0in, const float* __restrict__ ctx,
             const float* __restrict__ ctxc, const float* __restrict__ emb,
             const float* __restrict__ W_ih, const float* __restrict__ W_hh,
             const float* __restrict__ b_ih, const float* __restrict__ b_hh,
             const float* __restrict__ Wi_att, const float* __restrict__ bi_att,
             const float* __restrict__ Wo_att, const float* __restrict__ bo_att,
             const float* __restrict__ Wi_conv, const float* __restrict__ bi_conv,
             const float* __restrict__ Wo_conv, const float* __restrict__ bo_conv,
             float* __restrict__ out, float* __restrict__ ws)
{
  const int g = blockIdx.x, tid = threadIdx.x;

  // workspace (floats): EMBS [T*B][H] | H0,C0,H1,C1 ping-pong [2][BH] each
  float* EMBS = ws;
  float* H0 = EMBS + (size_t)T_ * BH;
  float* C0 = H0 + 2 * BH;
  float* H1 = C0 + 2 * BH;
  float* C1 = H1 + 2 * BH;

  // 64 KB LDS, phase-multiplexed:
  //  phase1: red0 @0 (64*17), red1 @1088 (64*17)
  //  phase2: xh @0, gv @2048, ct @4096, ocv @6144, part @8192 [2][8][512],
  //          ml @0 (after xh is dead)
  __shared__ float smem[16384];

  unsigned bar = __hip_atomic_load(&g_go, __ATOMIC_RELAXED,
                                   __HIP_MEMORY_SCOPE_AGENT);

  // ---- init: recurrent state + embedding gather ----
  // Ping parity rule: h_l(t) lands in ping (t&1) for layer 1 and ping
  // ~(t&1) for layer 0 (pipeline shift). Layer 0's first read (s=0) is
  // ping 0; layer 1's first read (s=1, pi=1) is ping 1 — so the INITIAL
  // h1/c1 must be stored in ping 1. (Round 2/3 bug: stored in ping 0,
  // feeding poison into the layer-1 recurrence.)
  {
    const int gid = g * NT + tid;
    if (gid < BH) {
      H0[gid]      = h0in[gid];
      C0[gid]      = c0in[gid];
      H1[BH + gid] = h0in[BH + gid];   // ping 1!
      C1[BH + gid] = c0in[BH + gid];   // ping 1!
    }
#pragma unroll
    for (int r = 0; r < 4; ++r) {
      const int tb = g * 4 + r;
      EMBS[(size_t)tb * H_ + tid] = emb[(size_t)inputs[tb] * H_ + tid];
    }
  }
  grid_barrier(++bar);

  // ================= PHASE 1: layer-pipelined LSTM chain =================
  // stage s: cell0 computes LSTM0(t=s) [threads 0..255],
  //          cell1 computes LSTM1(t=s-1) [threads 256..511].
  float* red0 = smem;
  float* red1 = smem + 1088;

  for (int s = 0; s <= T_; ++s) {
    const int pi = s & 1, qi = pi ^ 1;
    {
      const int cell = tid >> 8;
      const bool act = cell ? (s >= 1) : (s < T_);
      if (act) {
        const int tid2 = tid & 255;
        const int b = tid2 & 31, jj = (tid2 >> 5) & 1, ks2 = tid2 >> 6;
        const int j = g * 2 + jj;
        const float* x = cell ? (H0 + pi * BH) : (EMBS + (size_t)s * BH);
        const float* h = cell ? (H1 + pi * BH) : (H0 + pi * BH);
        const float* Wih = W_ih + (size_t)cell * 4 * H_ * H_;
        const float* Whh = W_hh + (size_t)cell * 4 * H_ * H_;
        float a0 = 0.f, a1 = 0.f, a2 = 0.f, a3 = 0.f;
#pragma unroll
        for (int sub = 0; sub < 2; ++sub) {
          const int ks = ks2 * 2 + sub;
          const float* src = (ks < 4) ? (x + b * H_ + ks * 128)
                                      : (h + b * H_ + (ks - 4) * 128);
          const float* wb = (ks < 4) ? Wih : Whh;
          const int koff = (ks & 3) * 128;
          const float* w0 = wb + ((size_t)0 * H_ + j) * H_ + koff;
          const float* w1 = wb + ((size_t)1 * H_ + j) * H_ + koff;
          const float* w2 = wb + ((size_t)2 * H_ + j) * H_ + koff;
          const float* w3 = wb + ((size_t)3 * H_ + j) * H_ + koff;
#pragma unroll 4
          for (int k = 0; k < 128; k += 4) {
            float4 x4 = *(const float4*)(src + k);
            a0 += dot4(x4, *(const float4*)(w0 + k));
            a1 += dot4(x4, *(const float4*)(w1 + k));
            a2 += dot4(x4, *(const float4*)(w2 + k));
            a3 += dot4(x4, *(const float4*)(w3 + k));
          }
        }
        float* red = cell ? red1 : red0;
        const int lane = tid2 & 63;
        red[lane * 17 + 0 * 4 + ks2] = a0;
        red[lane * 17 + 1 * 4 + ks2] = a1;
        red[lane * 17 + 2 * 4 + ks2] = a2;
        red[lane * 17 + 3 * 4 + ks2] = a3;
      }
    }
    __syncthreads();
    if (tid < 128) {
      const int cell = tid >> 6, lane = tid & 63;
      const bool act = cell ? (s >= 1) : (s < T_);
      if (act) {
        const int bb = lane & 31, j2 = lane >> 5;
        const int jo = g * 2 + j2;
        const float* red = cell ? red1 : red0;
        float gi = 0.f, gf = 0.f, gg = 0.f, go_ = 0.f;
#pragma unroll
        for (int k = 0; k < 4; ++k) {
          gi  += red[lane * 17 + 0 * 4 + k];
          gf  += red[lane * 17 + 1 * 4 + k];
          gg  += red[lane * 17 + 2 * 4 + k];
          go_ += red[lane * 17 + 3 * 4 + k];
        }
        const float* bi = b_ih + (size_t)cell * 4 * H_;
        const float* bh = b_hh + (size_t)cell * 4 * H_;
        gi  += bi[0 * H_ + jo] + bh[0 * H_ + jo];
        gf  += bi[1 * H_ + jo] + bh[1 * H_ + jo];
        gg  += bi[2 * H_ + jo] + bh[2 * H_ + jo];
        go_ += bi[3 * H_ + jo] + bh[3 * H_ + jo];
        float* Hs = cell ? H1 : H0;
        float* Cs = cell ? C1 : C0;
        const float cp = Cs[pi * BH + bb * H_ + jo];
        const float cn = sigm(gf) * cp + sigm(gi) * tanhf(gg);
        const float hn = sigm(go_) * tanhf(cn);
        Cs[qi * BH + bb * H_ + jo] = cn;
        Hs[qi * BH + bb * H_ + jo] = hn;
        if (cell)  // stash h1(t) in out[t]; consumed (then overwritten) by phase 2
          out[((size_t)(s - 1) * B_ + bb) * H_ + jo] = hn;
      }
    }
    grid_barrier(++bar);
  }

  // final h/c tail: h0(31)/c0(31) in ping 0; h1(31)/c1(31) in ping 1
  if (g < 128) {
    const int a = g >> 5;
    const int gid = (g & 31) * NT + tid;
    const float* srcp = (a == 0) ? H0 : (a == 1) ? (H1 + BH)
                       : (a == 2) ? C0 : (C1 + BH);
    out[(size_t)T_ * BH + (size_t)a * BH + gid] = srcp[gid];
  }

  // ================= PHASE 2: attention, barrier-free =================
  // WG = (b = g&31, tchunk = g>>5); handles 4 timesteps t = tc*4 + tt.
  const int b = g & 31, tc = g >> 5;
  float* xh   = smem;          // [4][512]
  float* gv   = smem + 2048;   // [4][512]
  float* ct   = smem + 4096;   // [4][512]
  float* ocv  = smem + 6144;   // [4][512]
  float* part = smem + 8192;   // [2][8][512]
  float* ml   = smem;          // [4][8][2] — reuses xh after out_conv

#pragma unroll
  for (int tt = 0; tt < 4; ++tt)
    xh[tt * H_ + tid] = out[((size_t)(tc * 4 + tt) * B_ + b) * H_ + tid];
  __syncthreads();

  // ---- gamma_conv = h1 @ Wi_conv^T + bi_conv (4 t's per thread-row) ----
  {
    const float* wr = Wi_conv + (size_t)tid * H_;
    float acc[4] = {0.f, 0.f, 0.f, 0.f};
#pragma unroll 4
    for (int k = 0; k < H_; k += 4) {
      float4 w4 = *(const float4*)(wr + k);
#pragma unroll
      for (int tt = 0; tt < 4; ++tt)
        acc[tt] += dot4(w4, *(const float4*)(xh + tt * H_ + k));
    }
    const float bj = bi_conv[tid];
#pragma unroll
    for (int tt = 0; tt < 4; ++tt) gv[tt * H_ + tid] = acc[tt] + bj;
  }
  __syncthreads();

  // ---- conv sweep: sigmoid-gated weighted sum over contexts_conv ----
  {
    const int w = tid >> 6, lane = tid & 63;
    float4 g0[4], g1[4];
#pragma unroll
    for (int tt = 0; tt < 4; ++tt) {
      g0[tt] = *(const float4*)(gv + tt * H_ + lane * 8);
      g1[tt] = *(const float4*)(gv + tt * H_ + lane * 8 + 4);
    }
    float4 a0[4], a1[4];
#pragma unroll
    for (int tt = 0; tt < 4; ++tt) { a0[tt] = make_float4(0,0,0,0); a1[tt] = make_float4(0,0,0,0); }
    const float* base = ctxc + (size_t)b * S_ * H_ + lane * 8;
    for (int s2 = w; s2 < S_; s2 += 8) {
      const float* xr = base + (size_t)s2 * H_;
      const float4 x0 = *(const float4*)(xr);
      const float4 x1 = *(const float4*)(xr + 4);
      float p[4];
#pragma unroll
      for (int tt = 0; tt < 4; ++tt)
        p[tt] = dot4(x0, g0[tt]) + dot4(x1, g1[tt]);
#pragma unroll
      for (int off = 32; off >= 1; off >>= 1) {
#pragma unroll
        for (int tt = 0; tt < 4; ++tt) p[tt] += __shfl_xor(p[tt], off, 64);
      }
#pragma unroll
      for (int tt = 0; tt < 4; ++tt) {
        const float wt = sigm(p[tt]);
        fma4(a0[tt], wt, x0); fma4(a1[tt], wt, x1);
      }
    }
    // two-round cross-wave reduction (part holds 2 t's at a time)
#pragma unroll
    for (int rnd = 0; rnd < 2; ++rnd) {
#pragma unroll
      for (int q = 0; q < 2; ++q) {
        const int tt = rnd * 2 + q;
        *(float4*)(part + ((size_t)q * 8 + w) * H_ + lane * 8)     = a0[tt];
        *(float4*)(part + ((size_t)q * 8 + w) * H_ + lane * 8 + 4) = a1[tt];
      }
      __syncthreads();
#pragma unroll
      for (int q = 0; q < 2; ++q) {
        float ssum = 0.f;
#pragma unroll
        for (int w8 = 0; w8 < 8; ++w8)
          ssum += part[((size_t)q * 8 + w8) * H_ + tid];
        ct[(rnd * 2 + q) * H_ + tid] = ssum;
      }
      __syncthreads();
    }
  }

  // ---- out_conv = tanh([ct_c, h1] @ Wo_conv^T + bo_conv) ----
  {
    const float* wr = Wo_conv + (size_t)tid * (2 * H_);
    float acc[4] = {0.f, 0.f, 0.f, 0.f};
#pragma unroll 4
    for (int k = 0; k < H_; k += 4) {
      float4 w4 = *(const float4*)(wr + k);
#pragma unroll
      for (int tt = 0; tt < 4; ++tt)
        acc[tt] += dot4(w4, *(const float4*)(ct + tt * H_ + k));
    }
#pragma unroll 4
    for (int k = 0; k < H_; k += 4) {
      float4 w4 = *(const float4*)(wr + H_ + k);
#pragma unroll
      for (int tt = 0; tt < 4; ++tt)
        acc[tt] += dot4(w4, *(const float4*)(xh + tt * H_ + k));
    }
    const float bj = bo_conv[tid];
#pragma unroll
    for (int tt = 0; tt < 4; ++tt) ocv[tt * H_ + tid] = tanhf(acc[tt] + bj);
  }
  __syncthreads();   // xh dead from here; ml may alias it

  // ---- gamma_att = out_conv @ Wi_att^T + bi_att ----
  {
    const float* wr = Wi_att + (size_t)tid * H_;
    float acc[4] = {0.f, 0.f, 0.f, 0.f};
#pragma unroll 4
    for (int k = 0; k < H_; k += 4) {
      float4 w4 = *(const float4*)(wr + k);
#pragma unroll
      for (int tt = 0; tt < 4; ++tt)
        acc[tt] += dot4(w4, *(const float4*)(ocv + tt * H_ + k));
    }
    const float bj = bi_att[tid];
#pragma unroll
    for (int tt = 0; tt < 4; ++tt) gv[tt * H_ + tid] = acc[tt] + bj;
  }
  __syncthreads();

  // ---- att sweep: online softmax weighted sum over contexts ----
  {
    const int w = tid >> 6, lane = tid & 63;
    float4 g0[4], g1[4];
#pragma unroll
    for (int tt = 0; tt < 4; ++tt) {
      g0[tt] = *(const float4*)(gv + tt * H_ + lane * 8);
      g1[tt] = *(const float4*)(gv + tt * H_ + lane * 8 + 4);
    }
    float4 a0[4], a1[4];
    float m[4], l[4];
#pragma unroll
    for (int tt = 0; tt < 4; ++tt) {
      a0[tt] = make_float4(0,0,0,0); a1[tt] = make_float4(0,0,0,0);
      m[tt] = -1e30f; l[tt] = 0.f;
    }
    const float* base = ctx + (size_t)b * S_ * H_ + lane * 8;
    for (int s2 = w; s2 < S_; s2 += 8) {
      const float* xr = base + (size_t)s2 * H_;
      const float4 x0 = *(const float4*)(xr);
      const float4 x1 = *(const float4*)(xr + 4);
      float p[4];
#pragma unroll
      for (int tt = 0; tt < 4; ++tt)
        p[tt] = dot4(x0, g0[tt]) + dot4(x1, g1[tt]);
#pragma unroll
      for (int off = 32; off >= 1; off >>= 1) {
#pragma unroll
        for (int tt = 0; tt < 4; ++tt) p[tt] += __shfl_xor(p[tt], off, 64);
      }
#pragma unroll
      for (int tt = 0; tt < 4; ++tt) {
        const float m2 = fmaxf(m[tt], p[tt]);
        const float f = expf(m[tt] - m2);
        const float e = expf(p[tt] - m2);
        l[tt] = l[tt] * f + e;
        scale_fma4(a0[tt], f, e, x0);
        scale_fma4(a1[tt], f, e, x1);
        m[tt] = m2;
      }
    }
    if (lane == 0) {
#pragma unroll
      for (int tt = 0; tt < 4; ++tt) {
        ml[(tt * 8 + w) * 2]     = m[tt];
        ml[(tt * 8 + w) * 2 + 1] = l[tt];
      }
    }
#pragma unroll
    for (int rnd = 0; rnd < 2; ++rnd) {
#pragma unroll
      for (int q = 0; q < 2; ++q) {
        const int tt = rnd * 2 + q;
        *(float4*)(part + ((size_t)q * 8 + w) * H_ + lane * 8)     = a0[tt];
        *(float4*)(part + ((size_t)q * 8 + w) * H_ + lane * 8 + 4) = a1[tt];
      }
      __syncthreads();
#pragma unroll
      for (int q = 0; q < 2; ++q) {
        const int tt = rnd * 2 + q;
        float M = ml[(tt * 8 + 0) * 2];
#pragma unroll
        for (int w8 = 1; w8 < 8; ++w8) M = fmaxf(M, ml[(tt * 8 + w8) * 2]);
        float L = 0.f, ssum = 0.f;
#pragma unroll
        for (int w8 = 0; w8 < 8; ++w8) {
          const float f = expf(ml[(tt * 8 + w8) * 2] - M);
          L    += f * ml[(tt * 8 + w8) * 2 + 1];
          ssum += f * part[((size_t)q * 8 + w8) * H_ + tid];
        }
        ct[tt * H_ + tid] = ssum / L;
      }
      __syncthreads();
    }
  }

  // ---- out[t] = tanh([ct, out_conv] @ Wo_att^T + bo_att) + out_conv ----
  {
    const float* wr = Wo_att + (size_t)tid * (2 * H_);
    float acc[4] = {0.f, 0.f, 0.f, 0.f};
#pragma unroll 4
    for (int k = 0; k < H_; k += 4) {
      float4 w4 = *(const float4*)(wr + k);
#pragma unroll
      for (int tt = 0; tt < 4; ++tt)
        acc[tt] += dot4(w4, *(const float4*)(ct + tt * H_ + k));
    }
#pragma unroll 4
    for (int k = 0; k < H_; k += 4) {
      float4 w4 = *(const float4*)(wr + H_ + k);
#pragma unroll
      for (int tt = 0; tt < 4; ++tt)
        acc[tt] += dot4(w4, *(const float4*)(ocv + tt * H_ + k));
    }
    const float bj = bo_att[tid];
#pragma unroll
    for (int tt = 0; tt < 4; ++tt)
      out[((size_t)(tc * 4 + tt) * B_ + b) * H_ + tid] =
          tanhf(acc[tt] + bj) + ocv[tt * H_ + tid];
  }
}

extern "C" void kernel_launch(void* const* d_in, const int* in_sizes, int n_in,
                              void* d_out, int out_size, void* d_ws, size_t ws_size,
                              hipStream_t stream) {
  rnn_all<<<dim3(NWG), dim3(NT), 0, stream>>>(
      (const int*)d_in[0],   (const float*)d_in[1],  (const float*)d_in[2],
      (const float*)d_in[3], (const float*)d_in[4],  (const float*)d_in[5],
      (const float*)d_in[6], (const float*)d_in[7],  (const float*)d_in[8],
      (const float*)d_in[9], (const float*)d_in[10], (const float*)d_in[11],
      (const float*)d_in[12],(const float*)d_in[13], (const float*)d_in[14],
      (const float*)d_in[15],(const float*)d_in[16], (const float*)d_in[17],
      (float*)d_out, (float*)d_ws);
}

// Round 5
// 1908.042 us; speedup vs baseline: 4.1978x; 1.1015x over previous
//
#include <hip/hip_runtime.h>
#include <math.h>

namespace {
constexpr int T_ = 32, B_ = 32, H_ = 512, S_ = 512;
constexpr int BH = B_ * H_;     // 16384
// ws float offsets
constexpr size_t O_EMBS = 0;                      // [T*B][H] 524288
constexpr size_t O_H0   = O_EMBS + (size_t)T_ * BH;  // 2*BH each
constexpr size_t O_C0   = O_H0 + 2 * BH;
constexpr size_t O_H1   = O_C0 + 2 * BH;
constexpr size_t O_C1   = O_H1 + 2 * BH;
constexpr size_t O_GC   = O_C1 + 2 * BH;          // gamma (conv, later att) [1024][512]
constexpr size_t O_CTC  = O_GC + (size_t)1024 * 512;  // ct (conv, later att)
constexpr size_t O_OCV  = O_CTC + (size_t)1024 * 512; // out_conv
}

// Monotonic barrier state (module scope: zero-init, survives replays, immune
// to 0xAA ws poison). Used only by k_lstm.
__device__ unsigned g_arrive[256] = {};
__device__ unsigned g_go = 0;

static __device__ __forceinline__ float sigm(float x) { return 1.0f / (1.0f + expf(-x)); }
static __device__ __forceinline__ float dot4(float4 a, float4 b) {
  return a.x * b.x + a.y * b.y + a.z * b.z + a.w * b.w;
}
static __device__ __forceinline__ void fma4(float4& a, float s, float4 x) {
  a.x += s * x.x; a.y += s * x.y; a.z += s * x.z; a.w += s * x.w;
}
static __device__ __forceinline__ void scale_fma4(float4& a, float f, float e, float4 x) {
  a.x = a.x * f + e * x.x; a.y = a.y * f + e * x.y;
  a.z = a.z * f + e * x.z; a.w = a.w * f + e * x.w;
}

static __device__ __forceinline__ void grid_barrier(unsigned target) {
  __syncthreads();
  if (threadIdx.x == 0)
    __hip_atomic_store(&g_arrive[blockIdx.x], target, __ATOMIC_RELEASE,
                       __HIP_MEMORY_SCOPE_AGENT);
  if (blockIdx.x == 0) {
    if (threadIdx.x < 64) {
      for (int i = threadIdx.x; i < 256; i += 64)
        while (__hip_atomic_load(&g_arrive[i], __ATOMIC_RELAXED,
                                 __HIP_MEMORY_SCOPE_AGENT) < target)
          __builtin_amdgcn_s_sleep(2);
    }
    __syncthreads();
    __builtin_amdgcn_fence(__ATOMIC_ACQUIRE, "agent");
    if (threadIdx.x == 0)
      __hip_atomic_store(&g_go, target, __ATOMIC_RELEASE,
                         __HIP_MEMORY_SCOPE_AGENT);
  }
  if (threadIdx.x == 0)
    while (__hip_atomic_load(&g_go, __ATOMIC_RELAXED,
                             __HIP_MEMORY_SCOPE_AGENT) < target)
      __builtin_amdgcn_s_sleep(2);
  __syncthreads();
  __builtin_amdgcn_fence(__ATOMIC_ACQUIRE, "agent");
}

// ---------------- K1: init state + embedding gather ----------------
__global__ __launch_bounds__(512)
void k_init(const int* __restrict__ inputs, const float* __restrict__ h0in,
            const float* __restrict__ c0in, const float* __restrict__ emb,
            float* __restrict__ ws) {
  const int g = blockIdx.x, tid = threadIdx.x;
  const int gid = g * 512 + tid;
  // Ping parity: layer-0 initial state in ping 0; layer-1 initial in ping 1.
  if (gid < BH) {
    ws[O_H0 + gid]      = h0in[gid];
    ws[O_C0 + gid]      = c0in[gid];
    ws[O_H1 + BH + gid] = h0in[BH + gid];
    ws[O_C1 + BH + gid] = c0in[BH + gid];
  }
#pragma unroll
  for (int r = 0; r < 4; ++r) {
    const int tb = g * 4 + r;
    ws[O_EMBS + (size_t)tb * H_ + tid] = emb[(size_t)inputs[tb] * H_ + tid];
  }
}

// ---------------- K2: persistent layer-pipelined LSTM chain ----------------
// Identical structure to the validated round-4 phase 1. Writes h1(t) rows to
// out[t] (scratch until final kernel overwrites) and final h/c tail.
__global__ __launch_bounds__(512)
void k_lstm(const float* __restrict__ W_ih, const float* __restrict__ W_hh,
            const float* __restrict__ b_ih, const float* __restrict__ b_hh,
            float* __restrict__ out, float* __restrict__ ws) {
  const int g = blockIdx.x, tid = threadIdx.x;
  float* EMBS = ws + O_EMBS;
  float* H0 = ws + O_H0;
  float* C0 = ws + O_C0;
  float* H1 = ws + O_H1;
  float* C1 = ws + O_C1;

  __shared__ float smem[2176];  // red0 @0 (64*17), red1 @1088
  float* red0 = smem;
  float* red1 = smem + 1088;

  unsigned bar = __hip_atomic_load(&g_go, __ATOMIC_RELAXED,
                                   __HIP_MEMORY_SCOPE_AGENT);

  for (int s = 0; s <= T_; ++s) {
    const int pi = s & 1, qi = pi ^ 1;
    {
      const int cell = tid >> 8;
      const bool act = cell ? (s >= 1) : (s < T_);
      if (act) {
        const int tid2 = tid & 255;
        const int b = tid2 & 31, jj = (tid2 >> 5) & 1, ks2 = tid2 >> 6;
        const int j = g * 2 + jj;
        const float* x = cell ? (H0 + pi * BH) : (EMBS + (size_t)s * BH);
        const float* h = cell ? (H1 + pi * BH) : (H0 + pi * BH);
        const float* Wih = W_ih + (size_t)cell * 4 * H_ * H_;
        const float* Whh = W_hh + (size_t)cell * 4 * H_ * H_;
        float a0 = 0.f, a1 = 0.f, a2 = 0.f, a3 = 0.f;
#pragma unroll
        for (int sub = 0; sub < 2; ++sub) {
          const int ks = ks2 * 2 + sub;
          const float* src = (ks < 4) ? (x + b * H_ + ks * 128)
                                      : (h + b * H_ + (ks - 4) * 128);
          const float* wb = (ks < 4) ? Wih : Whh;
          const int koff = (ks & 3) * 128;
          const float* w0 = wb + ((size_t)0 * H_ + j) * H_ + koff;
          const float* w1 = wb + ((size_t)1 * H_ + j) * H_ + koff;
          const float* w2 = wb + ((size_t)2 * H_ + j) * H_ + koff;
          const float* w3 = wb + ((size_t)3 * H_ + j) * H_ + koff;
#pragma unroll 4
          for (int k = 0; k < 128; k += 4) {
            float4 x4 = *(const float4*)(src + k);
            a0 += dot4(x4, *(const float4*)(w0 + k));
            a1 += dot4(x4, *(const float4*)(w1 + k));
            a2 += dot4(x4, *(const float4*)(w2 + k));
            a3 += dot4(x4, *(const float4*)(w3 + k));
          }
        }
        float* red = cell ? red1 : red0;
        const int lane = tid2 & 63;
        red[lane * 17 + 0 * 4 + ks2] = a0;
        red[lane * 17 + 1 * 4 + ks2] = a1;
        red[lane * 17 + 2 * 4 + ks2] = a2;
        red[lane * 17 + 3 * 4 + ks2] = a3;
      }
    }
    __syncthreads();
    if (tid < 128) {
      const int cell = tid >> 6, lane = tid & 63;
      const bool act = cell ? (s >= 1) : (s < T_);
      if (act) {
        const int bb = lane & 31, j2 = lane >> 5;
        const int jo = g * 2 + j2;
        const float* red = cell ? red1 : red0;
        float gi = 0.f, gf = 0.f, gg = 0.f, go_ = 0.f;
#pragma unroll
        for (int k = 0; k < 4; ++k) {
          gi  += red[lane * 17 + 0 * 4 + k];
          gf  += red[lane * 17 + 1 * 4 + k];
          gg  += red[lane * 17 + 2 * 4 + k];
          go_ += red[lane * 17 + 3 * 4 + k];
        }
        const float* bi = b_ih + (size_t)cell * 4 * H_;
        const float* bh = b_hh + (size_t)cell * 4 * H_;
        gi  += bi[0 * H_ + jo] + bh[0 * H_ + jo];
        gf  += bi[1 * H_ + jo] + bh[1 * H_ + jo];
        gg  += bi[2 * H_ + jo] + bh[2 * H_ + jo];
        go_ += bi[3 * H_ + jo] + bh[3 * H_ + jo];
        float* Hs = cell ? H1 : H0;
        float* Cs = cell ? C1 : C0;
        const float cp = Cs[pi * BH + bb * H_ + jo];
        const float cn = sigm(gf) * cp + sigm(gi) * tanhf(gg);
        const float hn = sigm(go_) * tanhf(cn);
        Cs[qi * BH + bb * H_ + jo] = cn;
        Hs[qi * BH + bb * H_ + jo] = hn;
        if (cell)  // stash h1(t) rows (XH) in out[t]
          out[((size_t)(s - 1) * B_ + bb) * H_ + jo] = hn;
      }
    }
    grid_barrier(++bar);
  }

  // final h/c tail: h0/c0 final in ping 0, h1/c1 final in ping 1
  if (g < 128) {
    const int a = g >> 5;
    const int gid = (g & 31) * 512 + tid;
    const float* srcp = (a == 0) ? (ws + O_H0) : (a == 1) ? (ws + O_H1 + BH)
                       : (a == 2) ? (ws + O_C0) : (ws + O_C1 + BH);
    out[(size_t)T_ * BH + (size_t)a * BH + gid] = srcp[gid];
  }
}

// ---------------- tiled GEMM: C[m][n] = ep(A[m][:] . W[n][:] + bias[n]) ----------------
// M=1024 (rows m = t*32+b), N=512, K = 512 (A1 only) or 1024 (A1 rows then A2 rows).
// tile 32x32, block 256, micro 2x2. All global loads coalesced; B transposed in LDS.
template<bool TANH, bool RES>
__global__ __launch_bounds__(256)
void k_gemm(const float* __restrict__ A1, const float* __restrict__ A2,
            const float* __restrict__ W, const float* __restrict__ bias,
            const float* __restrict__ res, float* __restrict__ C, int dualA) {
  const int bid = blockIdx.x, tid = threadIdx.x;
  const int m0 = (bid & 31) * 32, n0 = (bid >> 5) * 32;
  const int tx = tid & 15, ty = tid >> 4;          // micro: 2n x 2m
  const int lr = tid >> 5, lc = tid & 31;          // staging: 8 rows x 32 cols
  const int nsteps = dualA ? 32 : 16;
  const int Krow = dualA ? 1024 : 512;             // W row length
  __shared__ __align__(16) float Asm[32 * 33];
  __shared__ __align__(16) float Bsm[32 * 34];
  float acc00 = 0.f, acc01 = 0.f, acc10 = 0.f, acc11 = 0.f;

  for (int kt = 0; kt < nsteps; ++kt) {
    const float* A = (kt < 16) ? A1 : A2;
    const int ka = (kt < 16) ? kt * 32 : (kt - 16) * 32;
    const int kb = kt * 32;
    __syncthreads();
#pragma unroll
    for (int i = 0; i < 4; ++i) {
      const int row = lr + i * 8;
      Asm[row * 33 + lc] = A[(size_t)(m0 + row) * 512 + ka + lc];
      Bsm[lc * 34 + row] = W[(size_t)(n0 + row) * Krow + kb + lc];
    }
    __syncthreads();
#pragma unroll 8
    for (int k = 0; k < 32; ++k) {
      const float a0 = Asm[(ty * 2) * 33 + k];
      const float a1 = Asm[(ty * 2 + 1) * 33 + k];
      const float2 b = *(const float2*)&Bsm[k * 34 + tx * 2];
      acc00 += a0 * b.x; acc01 += a0 * b.y;
      acc10 += a1 * b.x; acc11 += a1 * b.y;
    }
  }
  const int n = n0 + tx * 2;
  const int m = m0 + ty * 2;
  const float bx = bias[n], by = bias[n + 1];
  float v00 = acc00 + bx, v01 = acc01 + by;
  float v10 = acc10 + bx, v11 = acc11 + by;
  if (TANH) { v00 = tanhf(v00); v01 = tanhf(v01); v10 = tanhf(v10); v11 = tanhf(v11); }
  if (RES) {
    v00 += res[(size_t)m * 512 + n];       v01 += res[(size_t)m * 512 + n + 1];
    v10 += res[(size_t)(m + 1) * 512 + n]; v11 += res[(size_t)(m + 1) * 512 + n + 1];
  }
  C[(size_t)m * 512 + n] = v00;            C[(size_t)m * 512 + n + 1] = v01;
  C[(size_t)(m + 1) * 512 + n] = v10;      C[(size_t)(m + 1) * 512 + n + 1] = v11;
}

// ---------------- K4: sigmoid-gated sweep over contexts_conv ----------------
// grid 1024 (bid = t*32 + b -> same-b WGs share an XCD), block 256 (4 waves).
__global__ __launch_bounds__(256)
void k_sweep_conv(const float* __restrict__ ctxc, const float* __restrict__ GC,
                  float* __restrict__ CTC) {
  const int bid = blockIdx.x, tid = threadIdx.x;
  const int b = bid & 31;
  const int w = tid >> 6, lane = tid & 63;
  const float* gl = GC + (size_t)bid * H_ + lane * 8;
  const float4 g0 = *(const float4*)gl;
  const float4 g1 = *(const float4*)(gl + 4);
  float4 a0 = {0, 0, 0, 0}, a1 = {0, 0, 0, 0};
  const float* base = ctxc + (size_t)b * S_ * H_ + lane * 8;
  for (int i = 0; i < 128; ++i) {
    const int s = i * 4 + w;
    const float* xr = base + (size_t)s * H_;
    const float4 x0 = *(const float4*)(xr);
    const float4 x1 = *(const float4*)(xr + 4);
    float p = dot4(x0, g0) + dot4(x1, g1);
#pragma unroll
    for (int off = 32; off >= 1; off >>= 1) p += __shfl_xor(p, off, 64);
    const float wt = sigm(p);
    fma4(a0, wt, x0); fma4(a1, wt, x1);
  }
  __shared__ __align__(16) float part[4 * 512];
  *(float4*)&part[w * 512 + lane * 8] = a0;
  *(float4*)&part[w * 512 + lane * 8 + 4] = a1;
  __syncthreads();
  float sA = 0.f, sB = 0.f;
#pragma unroll
  for (int w8 = 0; w8 < 4; ++w8) {
    sA += part[w8 * 512 + tid];
    sB += part[w8 * 512 + 256 + tid];
  }
  CTC[(size_t)bid * H_ + tid] = sA;
  CTC[(size_t)bid * H_ + 256 + tid] = sB;
}

// ---------------- K7: online-softmax sweep over contexts ----------------
__global__ __launch_bounds__(256)
void k_sweep_att(const float* __restrict__ ctx, const float* __restrict__ GA,
                 float* __restrict__ CT) {
  const int bid = blockIdx.x, tid = threadIdx.x;
  const int b = bid & 31;
  const int w = tid >> 6, lane = tid & 63;
  const float* gl = GA + (size_t)bid * H_ + lane * 8;
  const float4 g0 = *(const float4*)gl;
  const float4 g1 = *(const float4*)(gl + 4);
  float4 a0 = {0, 0, 0, 0}, a1 = {0, 0, 0, 0};
  float m = -1e30f, l = 0.f;
  const float* base = ctx + (size_t)b * S_ * H_ + lane * 8;
  for (int i = 0; i < 128; ++i) {
    const int s = i * 4 + w;
    const float* xr = base + (size_t)s * H_;
    const float4 x0 = *(const float4*)(xr);
    const float4 x1 = *(const float4*)(xr + 4);
    float p = dot4(x0, g0) + dot4(x1, g1);
#pragma unroll
    for (int off = 32; off >= 1; off >>= 1) p += __shfl_xor(p, off, 64);
    const float m2 = fmaxf(m, p);
    const float f = expf(m - m2);
    const float e = expf(p - m2);
    l = l * f + e;
    scale_fma4(a0, f, e, x0);
    scale_fma4(a1, f, e, x1);
    m = m2;
  }
  __shared__ __align__(16) float part[4 * 512 + 8];
  *(float4*)&part[w * 512 + lane * 8] = a0;
  *(float4*)&part[w * 512 + lane * 8 + 4] = a1;
  if (lane == 0) { part[2048 + w * 2] = m; part[2048 + w * 2 + 1] = l; }
  __syncthreads();
  float M = part[2048];
#pragma unroll
  for (int w8 = 1; w8 < 4; ++w8) M = fmaxf(M, part[2048 + w8 * 2]);
  float fac[4], L = 0.f;
#pragma unroll
  for (int w8 = 0; w8 < 4; ++w8) {
    fac[w8] = expf(part[2048 + w8 * 2] - M);
    L += fac[w8] * part[2048 + w8 * 2 + 1];
  }
  const float inv = 1.0f / L;
  float sA = 0.f, sB = 0.f;
#pragma unroll
  for (int w8 = 0; w8 < 4; ++w8) {
    sA += fac[w8] * part[w8 * 512 + tid];
    sB += fac[w8] * part[w8 * 512 + 256 + tid];
  }
  CT[(size_t)bid * H_ + tid] = sA * inv;
  CT[(size_t)bid * H_ + 256 + tid] = sB * inv;
}

extern "C" void kernel_launch(void* const* d_in, const int* in_sizes, int n_in,
                              void* d_out, int out_size, void* d_ws, size_t ws_size,
                              hipStream_t stream) {
  const int*   inputs  = (const int*)d_in[0];
  const float* h0in    = (const float*)d_in[1];
  const float* c0in    = (const float*)d_in[2];
  const float* ctx     = (const float*)d_in[3];
  const float* ctxc    = (const float*)d_in[4];
  const float* emb     = (const float*)d_in[5];
  const float* W_ih    = (const float*)d_in[6];
  const float* W_hh    = (const float*)d_in[7];
  const float* b_ih    = (const float*)d_in[8];
  const float* b_hh    = (const float*)d_in[9];
  const float* Wi_att  = (const float*)d_in[10];
  const float* bi_att  = (const float*)d_in[11];
  const float* Wo_att  = (const float*)d_in[12];
  const float* bo_att  = (const float*)d_in[13];
  const float* Wi_conv = (const float*)d_in[14];
  const float* bi_conv = (const float*)d_in[15];
  const float* Wo_conv = (const float*)d_in[16];
  const float* bo_conv = (const float*)d_in[17];
  float* out = (float*)d_out;
  float* ws  = (float*)d_ws;

  float* GC  = ws + O_GC;    // gamma_conv, then gamma_att
  float* CTC = ws + O_CTC;   // ct_conv, then ct_att
  float* OCV = ws + O_OCV;   // out_conv

  k_init<<<dim3(256), dim3(512), 0, stream>>>(inputs, h0in, c0in, emb, ws);
  k_lstm<<<dim3(256), dim3(512), 0, stream>>>(W_ih, W_hh, b_ih, b_hh, out, ws);
  // gamma_conv = XH @ Wi_conv^T + bi_conv   (XH stashed in out)
  k_gemm<false, false><<<dim3(512), dim3(256), 0, stream>>>(
      out, nullptr, Wi_conv, bi_conv, nullptr, GC, 0);
  k_sweep_conv<<<dim3(1024), dim3(256), 0, stream>>>(ctxc, GC, CTC);
  // out_conv = tanh([ct_c | XH] @ Wo_conv^T + bo_conv)
  k_gemm<true, false><<<dim3(512), dim3(256), 0, stream>>>(
      CTC, out, Wo_conv, bo_conv, nullptr, OCV, 1);
  // gamma_att = OCV @ Wi_att^T + bi_att
  k_gemm<false, false><<<dim3(512), dim3(256), 0, stream>>>(
      OCV, nullptr, Wi_att, bi_att, nullptr, GC, 0);
  k_sweep_att<<<dim3(1024), dim3(256), 0, stream>>>(ctx, GC, CTC);
  // out = tanh([ct | OCV] @ Wo_att^T + bo_att) + OCV
  k_gemm<true, true><<<dim3(512), dim3(256), 0, stream>>>(
      CTC, OCV, Wo_att, bo_att, OCV, out, 1);
}

// Round 6
// 1565.672 us; speedup vs baseline: 5.1158x; 1.2187x over previous
//
#include <hip/hip_runtime.h>
#include <math.h>

namespace {
constexpr int T_ = 32, B_ = 32, H_ = 512, S_ = 512;
constexpr int BH = B_ * H_;     // 16384
constexpr int LSTM_NWG = 512;
// ws float offsets
constexpr size_t O_EMBS = 0;                          // [T*B][H]
constexpr size_t O_H0   = O_EMBS + (size_t)T_ * BH;   // [2][BH]
constexpr size_t O_H1   = O_H0 + 2 * BH;              // [2][BH]
constexpr size_t O_GC   = O_H1 + 2 * BH;              // gamma (conv, later att) [1024][512]
constexpr size_t O_CTC  = O_GC + (size_t)1024 * 512;  // ct (conv, later att)
constexpr size_t O_OCV  = O_CTC + (size_t)1024 * 512; // out_conv
}

// Monotonic barrier state (zero-init at load, survives graph replays, immune
// to 0xAA ws poison). Used only by k_lstm.
__device__ unsigned g_arrive[LSTM_NWG] = {};
__device__ unsigned g_go = 0;

static __device__ __forceinline__ float sigm(float x) { return 1.0f / (1.0f + expf(-x)); }
static __device__ __forceinline__ float dot4(float4 a, float4 b) {
  return a.x * b.x + a.y * b.y + a.z * b.z + a.w * b.w;
}
static __device__ __forceinline__ void fma4(float4& a, float s, float4 x) {
  a.x += s * x.x; a.y += s * x.y; a.z += s * x.z; a.w += s * x.w;
}
static __device__ __forceinline__ void scale_fma4(float4& a, float f, float e, float4 x) {
  a.x = a.x * f + e * x.x; a.y = a.y * f + e * x.y;
  a.z = a.z * f + e * x.z; a.w = a.w * f + e * x.w;
}

// Central two-level barrier (validated round 4/5). Release: entry
// __syncthreads + tid0 RELEASE store. Acquire: agent fence by ALL threads
// after the final __syncthreads.
static __device__ __forceinline__ void grid_barrier(unsigned target) {
  __syncthreads();
  if (threadIdx.x == 0)
    __hip_atomic_store(&g_arrive[blockIdx.x], target, __ATOMIC_RELEASE,
                       __HIP_MEMORY_SCOPE_AGENT);
  if (blockIdx.x == 0) {
    if (threadIdx.x < 64) {
      for (int i = threadIdx.x; i < LSTM_NWG; i += 64)
        while (__hip_atomic_load(&g_arrive[i], __ATOMIC_RELAXED,
                                 __HIP_MEMORY_SCOPE_AGENT) < target)
          __builtin_amdgcn_s_sleep(2);
    }
    __syncthreads();
    __builtin_amdgcn_fence(__ATOMIC_ACQUIRE, "agent");
    if (threadIdx.x == 0)
      __hip_atomic_store(&g_go, target, __ATOMIC_RELEASE,
                         __HIP_MEMORY_SCOPE_AGENT);
  }
  if (threadIdx.x == 0)
    while (__hip_atomic_load(&g_go, __ATOMIC_RELAXED,
                             __HIP_MEMORY_SCOPE_AGENT) < target)
      __builtin_amdgcn_s_sleep(2);
  __syncthreads();
  __builtin_amdgcn_fence(__ATOMIC_ACQUIRE, "agent");
}

// ---------------- K1: init state + embedding gather ----------------
__global__ __launch_bounds__(512)
void k_init(const int* __restrict__ inputs, const float* __restrict__ h0in,
            const float* __restrict__ emb, float* __restrict__ ws) {
  const int g = blockIdx.x, tid = threadIdx.x;
  const int gid = g * 512 + tid;
  // Ping parity: layer-0 initial h in ping 0; layer-1 initial h in ping 1.
  if (gid < BH) {
    ws[O_H0 + gid]      = h0in[gid];
    ws[O_H1 + BH + gid] = h0in[BH + gid];
  }
#pragma unroll
  for (int r = 0; r < 4; ++r) {
    const int tb = g * 4 + r;
    ws[O_EMBS + (size_t)tb * H_ + tid] = emb[(size_t)inputs[tb] * H_ + tid];
  }
}

// ---------------- K2: persistent LSTM chain, LDS-resident weights ----------
// 512 WGs x 256 threads, 2 WGs/CU. WG = (cell = g>>8, column pair cp = g&255,
// columns j = cp*2 + jj). Pipeline: cell0 computes LSTM0(t=s), cell1 computes
// LSTM1(t=s-1). Weights (16 rows x 1024 K = 32 KB) preloaded to LDS once.
// c-state lives in registers of the 64 reduce threads (stage-invariant map).
__global__ __launch_bounds__(256, 2)
void k_lstm(const float* __restrict__ W_ih, const float* __restrict__ W_hh,
            const float* __restrict__ b_ih, const float* __restrict__ b_hh,
            const float* __restrict__ c0in, float* __restrict__ out,
            float* __restrict__ ws) {
  const int g = blockIdx.x, tid = threadIdx.x;
  const int cell = g >> 8, cp = g & 255;
  float* EMBS = ws + O_EMBS;
  float* H0 = ws + O_H0;
  float* H1 = ws + O_H1;

  __shared__ __align__(16) float wlds[2][4][1024];  // [jj][gate][k] 32 KB
  __shared__ float red[64 * 17];                    // 4.4 KB, padded stride

  // ---- one-time: stage this WG's weight rows into LDS ----
  {
    const float* Wih = W_ih + (size_t)cell * 4 * H_ * H_;
    const float* Whh = W_hh + (size_t)cell * 4 * H_ * H_;
#pragma unroll
    for (int l = 0; l < 8; ++l) {
      const int fidx = l * 256 + tid;     // float4 index 0..2047
      const int row = fidx >> 7;          // 0..15: [jj(1)][gt(2)][h2(1)]
      const int c4 = fidx & 127;
      const int h2 = row & 1, gt = (row >> 1) & 3, jj = row >> 3;
      const float* src = (h2 ? Whh : Wih) + ((size_t)gt * H_ + cp * 2 + jj) * H_;
      *(float4*)&wlds[jj][gt][h2 * 512 + c4 * 4] = *(const float4*)(src + c4 * 4);
    }
  }
  // ---- one-time: bias sums + c-state into reduce-thread registers ----
  float creg = 0.f, bsum0 = 0.f, bsum1 = 0.f, bsum2 = 0.f, bsum3 = 0.f;
  if (tid < 64) {
    const int bb = tid & 31, j2 = tid >> 5;
    const int jo = cp * 2 + j2;
    creg = c0in[cell * BH + bb * H_ + jo];
    const float* bi = b_ih + (size_t)cell * 4 * H_;
    const float* bh = b_hh + (size_t)cell * 4 * H_;
    bsum0 = bi[0 * H_ + jo] + bh[0 * H_ + jo];
    bsum1 = bi[1 * H_ + jo] + bh[1 * H_ + jo];
    bsum2 = bi[2 * H_ + jo] + bh[2 * H_ + jo];
    bsum3 = bi[3 * H_ + jo] + bh[3 * H_ + jo];
  }
  __syncthreads();

  const int b = tid & 31, jj = (tid >> 5) & 1, ks = tid >> 6;  // wave = ks
  const int lane = tid & 63;                                   // jj*32 + b

  unsigned bar = __hip_atomic_load(&g_go, __ATOMIC_RELAXED,
                                   __HIP_MEMORY_SCOPE_AGENT);

  for (int s = 0; s <= T_; ++s) {
    const int pi = s & 1, qi = pi ^ 1;
    const bool act = cell ? (s >= 1) : (s < T_);
    if (act) {
      const float* x = cell ? (H0 + pi * BH) : (EMBS + (size_t)s * BH);
      const float* h = cell ? (H1 + pi * BH) : (H0 + pi * BH);
      // thread K-slice [ks*256, ks*256+256): ks 0,1 -> x-part; 2,3 -> h-part
      const float* src = (ks < 2) ? (x + b * H_ + ks * 256)
                                  : (h + b * H_ + (ks - 2) * 256);
      const float* w0 = &wlds[jj][0][ks * 256];
      const float* w1 = &wlds[jj][1][ks * 256];
      const float* w2 = &wlds[jj][2][ks * 256];
      const float* w3 = &wlds[jj][3][ks * 256];
      float a0 = 0.f, a1 = 0.f, a2 = 0.f, a3 = 0.f;
#pragma unroll 8
      for (int k = 0; k < 256; k += 4) {
        const float4 x4 = *(const float4*)(src + k);
        a0 += dot4(x4, *(const float4*)(w0 + k));
        a1 += dot4(x4, *(const float4*)(w1 + k));
        a2 += dot4(x4, *(const float4*)(w2 + k));
        a3 += dot4(x4, *(const float4*)(w3 + k));
      }
      red[lane * 17 + 0 * 4 + ks] = a0;
      red[lane * 17 + 1 * 4 + ks] = a1;
      red[lane * 17 + 2 * 4 + ks] = a2;
      red[lane * 17 + 3 * 4 + ks] = a3;
    }
    __syncthreads();
    if (act && tid < 64) {
      const int bb = tid & 31, j2 = tid >> 5;
      const int jo = cp * 2 + j2;
      float gi = bsum0, gf = bsum1, gg = bsum2, go_ = bsum3;
#pragma unroll
      for (int k = 0; k < 4; ++k) {
        gi  += red[tid * 17 + 0 * 4 + k];
        gf  += red[tid * 17 + 1 * 4 + k];
        gg  += red[tid * 17 + 2 * 4 + k];
        go_ += red[tid * 17 + 3 * 4 + k];
      }
      const float cn = sigm(gf) * creg + sigm(gi) * tanhf(gg);
      const float hn = sigm(go_) * tanhf(cn);
      creg = cn;
      float* Hs = cell ? H1 : H0;
      Hs[qi * BH + bb * H_ + jo] = hn;
      if (cell)  // stash h1(t) rows (XH) in out[t]; overwritten by final GEMM
        out[((size_t)(s - 1) * B_ + bb) * H_ + jo] = hn;
      if (!cell && s == T_ - 1) {   // final h0/c0
        out[(size_t)T_ * BH + bb * H_ + jo]            = hn;
        out[(size_t)T_ * BH + 2 * BH + bb * H_ + jo]   = cn;
      }
      if (cell && s == T_) {        // final h1/c1
        out[(size_t)T_ * BH + BH + bb * H_ + jo]       = hn;
        out[(size_t)T_ * BH + 3 * BH + bb * H_ + jo]   = cn;
      }
    }
    if (s < T_) grid_barrier(++bar);
  }
}

// ---------------- tiled GEMM: C[m][n] = ep(A[m][:] . W[n][:] + bias[n]) ----
// M=1024 (rows m = t*32+b), N=512, K = 512 (A1) or 1024 (A1 rows | A2 rows).
template<bool TANH, bool RES>
__global__ __launch_bounds__(256)
void k_gemm(const float* __restrict__ A1, const float* __restrict__ A2,
            const float* __restrict__ W, const float* __restrict__ bias,
            const float* __restrict__ res, float* __restrict__ C, int dualA) {
  const int bid = blockIdx.x, tid = threadIdx.x;
  const int m0 = (bid & 31) * 32, n0 = (bid >> 5) * 32;
  const int tx = tid & 15, ty = tid >> 4;
  const int lr = tid >> 5, lc = tid & 31;
  const int nsteps = dualA ? 32 : 16;
  const int Krow = dualA ? 1024 : 512;
  __shared__ __align__(16) float Asm[32 * 33];
  __shared__ __align__(16) float Bsm[32 * 34];
  float acc00 = 0.f, acc01 = 0.f, acc10 = 0.f, acc11 = 0.f;

  for (int kt = 0; kt < nsteps; ++kt) {
    const float* A = (kt < 16) ? A1 : A2;
    const int ka = (kt < 16) ? kt * 32 : (kt - 16) * 32;
    const int kb = kt * 32;
    __syncthreads();
#pragma unroll
    for (int i = 0; i < 4; ++i) {
      const int row = lr + i * 8;
      Asm[row * 33 + lc] = A[(size_t)(m0 + row) * 512 + ka + lc];
      Bsm[lc * 34 + row] = W[(size_t)(n0 + row) * Krow + kb + lc];
    }
    __syncthreads();
#pragma unroll 8
    for (int k = 0; k < 32; ++k) {
      const float a0 = Asm[(ty * 2) * 33 + k];
      const float a1 = Asm[(ty * 2 + 1) * 33 + k];
      const float2 bv = *(const float2*)&Bsm[k * 34 + tx * 2];
      acc00 += a0 * bv.x; acc01 += a0 * bv.y;
      acc10 += a1 * bv.x; acc11 += a1 * bv.y;
    }
  }
  const int n = n0 + tx * 2;
  const int m = m0 + ty * 2;
  const float bx = bias[n], by = bias[n + 1];
  float v00 = acc00 + bx, v01 = acc01 + by;
  float v10 = acc10 + bx, v11 = acc11 + by;
  if (TANH) { v00 = tanhf(v00); v01 = tanhf(v01); v10 = tanhf(v10); v11 = tanhf(v11); }
  if (RES) {
    v00 += res[(size_t)m * 512 + n];       v01 += res[(size_t)m * 512 + n + 1];
    v10 += res[(size_t)(m + 1) * 512 + n]; v11 += res[(size_t)(m + 1) * 512 + n + 1];
  }
  C[(size_t)m * 512 + n] = v00;            C[(size_t)m * 512 + n + 1] = v01;
  C[(size_t)(m + 1) * 512 + n] = v10;      C[(size_t)(m + 1) * 512 + n + 1] = v11;
}

// ---------------- K4: sigmoid-gated sweep over contexts_conv ----------------
__global__ __launch_bounds__(256)
void k_sweep_conv(const float* __restrict__ ctxc, const float* __restrict__ GC,
                  float* __restrict__ CTC) {
  const int bid = blockIdx.x, tid = threadIdx.x;
  const int b = bid & 31;
  const int w = tid >> 6, lane = tid & 63;
  const float* gl = GC + (size_t)bid * H_ + lane * 8;
  const float4 g0 = *(const float4*)gl;
  const float4 g1 = *(const float4*)(gl + 4);
  float4 a0 = {0, 0, 0, 0}, a1 = {0, 0, 0, 0};
  const float* base = ctxc + (size_t)b * S_ * H_ + lane * 8;
  for (int i = 0; i < 128; ++i) {
    const int s = i * 4 + w;
    const float* xr = base + (size_t)s * H_;
    const float4 x0 = *(const float4*)(xr);
    const float4 x1 = *(const float4*)(xr + 4);
    float p = dot4(x0, g0) + dot4(x1, g1);
#pragma unroll
    for (int off = 32; off >= 1; off >>= 1) p += __shfl_xor(p, off, 64);
    const float wt = sigm(p);
    fma4(a0, wt, x0); fma4(a1, wt, x1);
  }
  __shared__ __align__(16) float part[4 * 512];
  *(float4*)&part[w * 512 + lane * 8] = a0;
  *(float4*)&part[w * 512 + lane * 8 + 4] = a1;
  __syncthreads();
  float sA = 0.f, sB = 0.f;
#pragma unroll
  for (int w8 = 0; w8 < 4; ++w8) {
    sA += part[w8 * 512 + tid];
    sB += part[w8 * 512 + 256 + tid];
  }
  CTC[(size_t)bid * H_ + tid] = sA;
  CTC[(size_t)bid * H_ + 256 + tid] = sB;
}

// ---------------- K7: online-softmax sweep over contexts ----------------
__global__ __launch_bounds__(256)
void k_sweep_att(const float* __restrict__ ctx, const float* __restrict__ GA,
                 float* __restrict__ CT) {
  const int bid = blockIdx.x, tid = threadIdx.x;
  const int b = bid & 31;
  const int w = tid >> 6, lane = tid & 63;
  const float* gl = GA + (size_t)bid * H_ + lane * 8;
  const float4 g0 = *(const float4*)gl;
  const float4 g1 = *(const float4*)(gl + 4);
  float4 a0 = {0, 0, 0, 0}, a1 = {0, 0, 0, 0};
  float m = -1e30f, l = 0.f;
  const float* base = ctx + (size_t)b * S_ * H_ + lane * 8;
  for (int i = 0; i < 128; ++i) {
    const int s = i * 4 + w;
    const float* xr = base + (size_t)s * H_;
    const float4 x0 = *(const float4*)(xr);
    const float4 x1 = *(const float4*)(xr + 4);
    float p = dot4(x0, g0) + dot4(x1, g1);
#pragma unroll
    for (int off = 32; off >= 1; off >>= 1) p += __shfl_xor(p, off, 64);
    const float m2 = fmaxf(m, p);
    const float f = expf(m - m2);
    const float e = expf(p - m2);
    l = l * f + e;
    scale_fma4(a0, f, e, x0);
    scale_fma4(a1, f, e, x1);
    m = m2;
  }
  __shared__ __align__(16) float part[4 * 512 + 8];
  *(float4*)&part[w * 512 + lane * 8] = a0;
  *(float4*)&part[w * 512 + lane * 8 + 4] = a1;
  if (lane == 0) { part[2048 + w * 2] = m; part[2048 + w * 2 + 1] = l; }
  __syncthreads();
  float M = part[2048];
#pragma unroll
  for (int w8 = 1; w8 < 4; ++w8) M = fmaxf(M, part[2048 + w8 * 2]);
  float fac[4], L = 0.f;
#pragma unroll
  for (int w8 = 0; w8 < 4; ++w8) {
    fac[w8] = expf(part[2048 + w8 * 2] - M);
    L += fac[w8] * part[2048 + w8 * 2 + 1];
  }
  const float inv = 1.0f / L;
  float sA = 0.f, sB = 0.f;
#pragma unroll
  for (int w8 = 0; w8 < 4; ++w8) {
    sA += fac[w8] * part[w8 * 512 + tid];
    sB += fac[w8] * part[w8 * 512 + 256 + tid];
  }
  CT[(size_t)bid * H_ + tid] = sA * inv;
  CT[(size_t)bid * H_ + 256 + tid] = sB * inv;
}

extern "C" void kernel_launch(void* const* d_in, const int* in_sizes, int n_in,
                              void* d_out, int out_size, void* d_ws, size_t ws_size,
                              hipStream_t stream) {
  const int*   inputs  = (const int*)d_in[0];
  const float* h0in    = (const float*)d_in[1];
  const float* c0in    = (const float*)d_in[2];
  const float* ctx     = (const float*)d_in[3];
  const float* ctxc    = (const float*)d_in[4];
  const float* emb     = (const float*)d_in[5];
  const float* W_ih    = (const float*)d_in[6];
  const float* W_hh    = (const float*)d_in[7];
  const float* b_ih    = (const float*)d_in[8];
  const float* b_hh    = (const float*)d_in[9];
  const float* Wi_att  = (const float*)d_in[10];
  const float* bi_att  = (const float*)d_in[11];
  const float* Wo_att  = (const float*)d_in[12];
  const float* bo_att  = (const float*)d_in[13];
  const float* Wi_conv = (const float*)d_in[14];
  const float* bi_conv = (const float*)d_in[15];
  const float* Wo_conv = (const float*)d_in[16];
  const float* bo_conv = (const float*)d_in[17];
  float* out = (float*)d_out;
  float* ws  = (float*)d_ws;

  float* GC  = ws + O_GC;    // gamma_conv, then gamma_att
  float* CTC = ws + O_CTC;   // ct_conv, then ct_att
  float* OCV = ws + O_OCV;   // out_conv

  k_init<<<dim3(256), dim3(512), 0, stream>>>(inputs, h0in, emb, ws);
  k_lstm<<<dim3(LSTM_NWG), dim3(256), 0, stream>>>(W_ih, W_hh, b_ih, b_hh,
                                                   c0in, out, ws);
  // gamma_conv = XH @ Wi_conv^T + bi_conv   (XH stashed in out)
  k_gemm<false, false><<<dim3(512), dim3(256), 0, stream>>>(
      out, nullptr, Wi_conv, bi_conv, nullptr, GC, 0);
  k_sweep_conv<<<dim3(1024), dim3(256), 0, stream>>>(ctxc, GC, CTC);
  // out_conv = tanh([ct_c | XH] @ Wo_conv^T + bo_conv)
  k_gemm<true, false><<<dim3(512), dim3(256), 0, stream>>>(
      CTC, out, Wo_conv, bo_conv, nullptr, OCV, 1);
  // gamma_att = OCV @ Wi_att^T + bi_att
  k_gemm<false, false><<<dim3(512), dim3(256), 0, stream>>>(
      OCV, nullptr, Wi_att, bi_att, nullptr, GC, 0);
  k_sweep_att<<<dim3(1024), dim3(256), 0, stream>>>(ctx, GC, CTC);
  // out = tanh([ct | OCV] @ Wo_att^T + bo_att) + OCV
  k_gemm<true, true><<<dim3(512), dim3(256), 0, stream>>>(
      CTC, OCV, Wo_att, bo_att, OCV, out, 1);
}

// Round 7
// 760.778 us; speedup vs baseline: 10.5282x; 2.0580x over previous
//
#include <hip/hip_runtime.h>
#include <math.h>

namespace {
constexpr int T_ = 32, B_ = 32, H_ = 512, S_ = 512;
constexpr int BH = B_ * H_;     // 16384
constexpr int LSTM_NWG = 512;
// ws float offsets
constexpr size_t O_EMBS = 0;                          // [T*B][H]
constexpr size_t O_H0   = O_EMBS + (size_t)T_ * BH;   // [2][BH]
constexpr size_t O_H1   = O_H0 + 2 * BH;              // [2][BH]
constexpr size_t O_GC   = O_H1 + 2 * BH;              // gamma (conv, later att) [1024][512]
constexpr size_t O_CTC  = O_GC + (size_t)1024 * 512;  // ct (conv, later att)
constexpr size_t O_OCV  = O_CTC + (size_t)1024 * 512; // out_conv
}

// Monotonic barrier state (zero-init at load, survives graph replays, immune
// to 0xAA ws poison). Used only by k_lstm.
__device__ unsigned g_arrive[LSTM_NWG] = {};
__device__ unsigned g_go = 0;

static __device__ __forceinline__ float sigm(float x) { return 1.0f / (1.0f + expf(-x)); }
static __device__ __forceinline__ float dot4(float4 a, float4 b) {
  return a.x * b.x + a.y * b.y + a.z * b.z + a.w * b.w;
}
static __device__ __forceinline__ void fma4(float4& a, float s, float4 x) {
  a.x += s * x.x; a.y += s * x.y; a.z += s * x.z; a.w += s * x.w;
}
static __device__ __forceinline__ void scale_fma4(float4& a, float f, float e, float4 x) {
  a.x = a.x * f + e * x.x; a.y = a.y * f + e * x.y;
  a.z = a.z * f + e * x.z; a.w = a.w * f + e * x.w;
}

static __device__ __forceinline__ float coh_load(const float* p) {
  return __hip_atomic_load(p, __ATOMIC_RELAXED, __HIP_MEMORY_SCOPE_AGENT);
}
static __device__ __forceinline__ void coh_store(float* p, float v) {
  __hip_atomic_store(p, v, __ATOMIC_RELAXED, __HIP_MEMORY_SCOPE_AGENT);
}

// Fence-free grid barrier. All cross-WG data moves via sc1 (device-coherent)
// accesses that bypass L2, so no cache invalidate/writeback is needed here —
// only store-completion (vmcnt) + flag atomics. L2 keeps EMBS/weights hot.
static __device__ __forceinline__ void grid_barrier_light(unsigned target) {
  asm volatile("s_waitcnt vmcnt(0)" ::: "memory");  // drain own sc1 h-stores
  __syncthreads();
  if (threadIdx.x == 0)
    __hip_atomic_store(&g_arrive[blockIdx.x], target, __ATOMIC_RELAXED,
                       __HIP_MEMORY_SCOPE_AGENT);
  if (blockIdx.x == 0) {
    for (int i = threadIdx.x; i < LSTM_NWG; i += 256)
      while (__hip_atomic_load(&g_arrive[i], __ATOMIC_RELAXED,
                               __HIP_MEMORY_SCOPE_AGENT) < target)
        __builtin_amdgcn_s_sleep(1);
    __syncthreads();
    if (threadIdx.x == 0)
      __hip_atomic_store(&g_go, target, __ATOMIC_RELAXED,
                         __HIP_MEMORY_SCOPE_AGENT);
  }
  if (threadIdx.x == 0)
    while (__hip_atomic_load(&g_go, __ATOMIC_RELAXED,
                             __HIP_MEMORY_SCOPE_AGENT) < target)
      __builtin_amdgcn_s_sleep(1);
  __syncthreads();
  asm volatile("" ::: "memory");   // compiler barrier: no load hoisting
}

// ---------------- K1: init state + embedding gather ----------------
__global__ __launch_bounds__(512)
void k_init(const int* __restrict__ inputs, const float* __restrict__ h0in,
            const float* __restrict__ emb, float* __restrict__ ws) {
  const int g = blockIdx.x, tid = threadIdx.x;
  const int gid = g * 512 + tid;
  // Ping parity: layer-0 initial h in ping 0; layer-1 initial h in ping 1.
  if (gid < BH) {
    ws[O_H0 + gid]      = h0in[gid];
    ws[O_H1 + BH + gid] = h0in[BH + gid];
  }
#pragma unroll
  for (int r = 0; r < 4; ++r) {
    const int tb = g * 4 + r;
    ws[O_EMBS + (size_t)tb * H_ + tid] = emb[(size_t)inputs[tb] * H_ + tid];
  }
}

// ---------------- K2: persistent LSTM chain ----------------
// 512 WGs x 256 threads, 2 WGs/CU. WG = (cell = g>>8, column pair cp = g&255).
// Weights LDS-resident (32 KB, loaded once, normal cached loads).
// Cross-stage h state exchanged ONLY via sc1 loads/stores (L2-bypassing):
// producer reduce threads coh_store hn; consumers cooperatively stage H0/H1
// into LDS with coalesced coh_loads (4 chunks x 128 k-cols x 32 b).
// c-state in registers of reduce threads. Barrier is fence-free.
__global__ __launch_bounds__(256, 2)
void k_lstm(const float* __restrict__ W_ih, const float* __restrict__ W_hh,
            const float* __restrict__ b_ih, const float* __restrict__ b_hh,
            const float* __restrict__ c0in, float* __restrict__ out,
            float* __restrict__ ws) {
  const int g = blockIdx.x, tid = threadIdx.x;
  const int cell = g >> 8, cp = g & 255;
  float* EMBS = ws + O_EMBS;
  float* H0 = ws + O_H0;
  float* H1 = ws + O_H1;

  __shared__ __align__(16) float wlds[2][4][1024];   // [jj][gate][x|h] 32 KB
  __shared__ __align__(16) float stg0[32 * 132];     // staged H chunk (pad 132)
  __shared__ __align__(16) float stg1[32 * 132];
  __shared__ float red[64 * 17];

  // ---- one-time: stage this WG's weight rows into LDS (normal loads) ----
  {
    const float* Wih = W_ih + (size_t)cell * 4 * H_ * H_;
    const float* Whh = W_hh + (size_t)cell * 4 * H_ * H_;
#pragma unroll
    for (int l = 0; l < 8; ++l) {
      const int fidx = l * 256 + tid;     // float4 index 0..2047
      const int row = fidx >> 7;          // [jj(1)][gt(2)][h2(1)]
      const int c4 = fidx & 127;
      const int h2 = row & 1, gt = (row >> 1) & 3, jj = row >> 3;
      const float* src = (h2 ? Whh : Wih) + ((size_t)gt * H_ + cp * 2 + jj) * H_;
      *(float4*)&wlds[jj][gt][h2 * 512 + c4 * 4] = *(const float4*)(src + c4 * 4);
    }
  }
  // ---- one-time: bias sums + c-state into reduce-thread registers ----
  float creg = 0.f, bsum0 = 0.f, bsum1 = 0.f, bsum2 = 0.f, bsum3 = 0.f;
  if (tid < 64) {
    const int bb = tid & 31, j2 = tid >> 5;
    const int jo = cp * 2 + j2;
    creg = c0in[cell * BH + bb * H_ + jo];
    const float* bi = b_ih + (size_t)cell * 4 * H_;
    const float* bh = b_hh + (size_t)cell * 4 * H_;
    bsum0 = bi[0 * H_ + jo] + bh[0 * H_ + jo];
    bsum1 = bi[1 * H_ + jo] + bh[1 * H_ + jo];
    bsum2 = bi[2 * H_ + jo] + bh[2 * H_ + jo];
    bsum3 = bi[3 * H_ + jo] + bh[3 * H_ + jo];
  }
  __syncthreads();

  const int b = tid & 31, jj = (tid >> 5) & 1, ks = tid >> 6;
  const int lane = tid & 63;       // jj*32 + b

  unsigned bar = __hip_atomic_load(&g_go, __ATOMIC_RELAXED,
                                   __HIP_MEMORY_SCOPE_AGENT);

  for (int s = 0; s <= T_; ++s) {
    const int pi = s & 1, qi = pi ^ 1;
    const bool act = cell ? (s >= 1) : (s < T_);   // WG-uniform
    float a0 = 0.f, a1 = 0.f, a2 = 0.f, a3 = 0.f;

    if (act) {
      // ---- cell0 x-part: EMBS, normal cached loads (L2-hot, no fences) ----
      if (cell == 0) {
        const float* xs = EMBS + (size_t)s * BH + b * H_ + ks * 128;
        const float* wx0 = &wlds[jj][0][ks * 128];
        const float* wx1 = &wlds[jj][1][ks * 128];
        const float* wx2 = &wlds[jj][2][ks * 128];
        const float* wx3 = &wlds[jj][3][ks * 128];
#pragma unroll 8
        for (int k = 0; k < 128; k += 4) {
          const float4 x4 = *(const float4*)(xs + k);
          a0 += dot4(x4, *(const float4*)(wx0 + k));
          a1 += dot4(x4, *(const float4*)(wx1 + k));
          a2 += dot4(x4, *(const float4*)(wx2 + k));
          a3 += dot4(x4, *(const float4*)(wx3 + k));
        }
      }
      // ---- staged chunks: 4 x 128 k-cols of H0 (and H1 for cell1) ----
      const float* H0p = H0 + pi * BH;
      const float* H1p = H1 + pi * BH;
      for (int c = 0; c < 4; ++c) {
        {  // coalesced sc1 gather -> LDS (gather to regs first: loads pipeline)
          float v0[16];
#pragma unroll
          for (int i = 0; i < 16; ++i) {
            const int d = tid + i * 256;          // 0..4095
            const int bb2 = d >> 7, kk = d & 127;
            v0[i] = coh_load(H0p + bb2 * H_ + c * 128 + kk);
          }
          if (cell) {
            float v1[16];
#pragma unroll
            for (int i = 0; i < 16; ++i) {
              const int d = tid + i * 256;
              const int bb2 = d >> 7, kk = d & 127;
              v1[i] = coh_load(H1p + bb2 * H_ + c * 128 + kk);
            }
#pragma unroll
            for (int i = 0; i < 16; ++i) {
              const int d = tid + i * 256;
              const int bb2 = d >> 7, kk = d & 127;
              stg1[bb2 * 132 + kk] = v1[i];
            }
          }
#pragma unroll
          for (int i = 0; i < 16; ++i) {
            const int d = tid + i * 256;
            const int bb2 = d >> 7, kk = d & 127;
            stg0[bb2 * 132 + kk] = v0[i];
          }
        }
        __syncthreads();
        {  // compute this thread's k-subrange [c*128 + ks*32, +32)
          const int kb = c * 128 + ks * 32;
          if (cell) {  // x-part from staged H0
            const float* sd = &stg0[b * 132 + ks * 32];
            const float* w0 = &wlds[jj][0][kb];
            const float* w1 = &wlds[jj][1][kb];
            const float* w2 = &wlds[jj][2][kb];
            const float* w3 = &wlds[jj][3][kb];
#pragma unroll
            for (int k = 0; k < 32; k += 4) {
              const float4 x4 = *(const float4*)(sd + k);
              a0 += dot4(x4, *(const float4*)(w0 + k));
              a1 += dot4(x4, *(const float4*)(w1 + k));
              a2 += dot4(x4, *(const float4*)(w2 + k));
              a3 += dot4(x4, *(const float4*)(w3 + k));
            }
          }
          // h-part: cell0 from stg0 (H0), cell1 from stg1 (H1)
          const float* hd = cell ? &stg1[b * 132 + ks * 32]
                                 : &stg0[b * 132 + ks * 32];
          const float* u0 = &wlds[jj][0][512 + kb];
          const float* u1 = &wlds[jj][1][512 + kb];
          const float* u2 = &wlds[jj][2][512 + kb];
          const float* u3 = &wlds[jj][3][512 + kb];
#pragma unroll
          for (int k = 0; k < 32; k += 4) {
            const float4 h4 = *(const float4*)(hd + k);
            a0 += dot4(h4, *(const float4*)(u0 + k));
            a1 += dot4(h4, *(const float4*)(u1 + k));
            a2 += dot4(h4, *(const float4*)(u2 + k));
            a3 += dot4(h4, *(const float4*)(u3 + k));
          }
        }
        __syncthreads();
      }
      red[lane * 17 + 0 * 4 + ks] = a0;
      red[lane * 17 + 1 * 4 + ks] = a1;
      red[lane * 17 + 2 * 4 + ks] = a2;
      red[lane * 17 + 3 * 4 + ks] = a3;
    }
    __syncthreads();
    if (act && tid < 64) {
      const int bb = tid & 31, j2 = tid >> 5;
      const int jo = cp * 2 + j2;
      float gi = bsum0, gf = bsum1, gg = bsum2, go_ = bsum3;
#pragma unroll
      for (int k = 0; k < 4; ++k) {
        gi  += red[tid * 17 + 0 * 4 + k];
        gf  += red[tid * 17 + 1 * 4 + k];
        gg  += red[tid * 17 + 2 * 4 + k];
        go_ += red[tid * 17 + 3 * 4 + k];
      }
      const float cn = sigm(gf) * creg + sigm(gi) * tanhf(gg);
      const float hn = sigm(go_) * tanhf(cn);
      creg = cn;
      float* Hs = cell ? H1 : H0;
      coh_store(&Hs[qi * BH + bb * H_ + jo], hn);   // sc1: LLC-visible
      if (cell)  // stash h1(t) rows (XH) in out[t] (normal store; next kernel)
        out[((size_t)(s - 1) * B_ + bb) * H_ + jo] = hn;
      if (!cell && s == T_ - 1) {   // final h0/c0
        out[(size_t)T_ * BH + bb * H_ + jo]            = hn;
        out[(size_t)T_ * BH + 2 * BH + bb * H_ + jo]   = cn;
      }
      if (cell && s == T_) {        // final h1/c1
        out[(size_t)T_ * BH + BH + bb * H_ + jo]       = hn;
        out[(size_t)T_ * BH + 3 * BH + bb * H_ + jo]   = cn;
      }
    }
    if (s < T_) grid_barrier_light(++bar);
  }
}

// ---------------- tiled GEMM: C[m][n] = ep(A[m][:] . W[n][:] + bias[n]) ----
// M=1024 (rows m = t*32+b), N=512, K = 512 (A1) or 1024 (A1 rows | A2 rows).
template<bool TANH, bool RES>
__global__ __launch_bounds__(256)
void k_gemm(const float* __restrict__ A1, const float* __restrict__ A2,
            const float* __restrict__ W, const float* __restrict__ bias,
            const float* __restrict__ res, float* __restrict__ C, int dualA) {
  const int bid = blockIdx.x, tid = threadIdx.x;
  const int m0 = (bid & 31) * 32, n0 = (bid >> 5) * 32;
  const int tx = tid & 15, ty = tid >> 4;
  const int lr = tid >> 5, lc = tid & 31;
  const int nsteps = dualA ? 32 : 16;
  const int Krow = dualA ? 1024 : 512;
  __shared__ __align__(16) float Asm[32 * 33];
  __shared__ __align__(16) float Bsm[32 * 34];
  float acc00 = 0.f, acc01 = 0.f, acc10 = 0.f, acc11 = 0.f;

  for (int kt = 0; kt < nsteps; ++kt) {
    const float* A = (kt < 16) ? A1 : A2;
    const int ka = (kt < 16) ? kt * 32 : (kt - 16) * 32;
    const int kb = kt * 32;
    __syncthreads();
#pragma unroll
    for (int i = 0; i < 4; ++i) {
      const int row = lr + i * 8;
      Asm[row * 33 + lc] = A[(size_t)(m0 + row) * 512 + ka + lc];
      Bsm[lc * 34 + row] = W[(size_t)(n0 + row) * Krow + kb + lc];
    }
    __syncthreads();
#pragma unroll 8
    for (int k = 0; k < 32; ++k) {
      const float a0 = Asm[(ty * 2) * 33 + k];
      const float a1 = Asm[(ty * 2 + 1) * 33 + k];
      const float2 bv = *(const float2*)&Bsm[k * 34 + tx * 2];
      acc00 += a0 * bv.x; acc01 += a0 * bv.y;
      acc10 += a1 * bv.x; acc11 += a1 * bv.y;
    }
  }
  const int n = n0 + tx * 2;
  const int m = m0 + ty * 2;
  const float bx = bias[n], by = bias[n + 1];
  float v00 = acc00 + bx, v01 = acc01 + by;
  float v10 = acc10 + bx, v11 = acc11 + by;
  if (TANH) { v00 = tanhf(v00); v01 = tanhf(v01); v10 = tanhf(v10); v11 = tanhf(v11); }
  if (RES) {
    v00 += res[(size_t)m * 512 + n];       v01 += res[(size_t)m * 512 + n + 1];
    v10 += res[(size_t)(m + 1) * 512 + n]; v11 += res[(size_t)(m + 1) * 512 + n + 1];
  }
  C[(size_t)m * 512 + n] = v00;            C[(size_t)m * 512 + n + 1] = v01;
  C[(size_t)(m + 1) * 512 + n] = v10;      C[(size_t)(m + 1) * 512 + n + 1] = v11;
}

// ---------------- K4: sigmoid-gated sweep over contexts_conv ----------------
__global__ __launch_bounds__(256)
void k_sweep_conv(const float* __restrict__ ctxc, const float* __restrict__ GC,
                  float* __restrict__ CTC) {
  const int bid = blockIdx.x, tid = threadIdx.x;
  const int b = bid & 31;
  const int w = tid >> 6, lane = tid & 63;
  const float* gl = GC + (size_t)bid * H_ + lane * 8;
  const float4 g0 = *(const float4*)gl;
  const float4 g1 = *(const float4*)(gl + 4);
  float4 a0 = {0, 0, 0, 0}, a1 = {0, 0, 0, 0};
  const float* base = ctxc + (size_t)b * S_ * H_ + lane * 8;
  for (int i = 0; i < 128; ++i) {
    const int s = i * 4 + w;
    const float* xr = base + (size_t)s * H_;
    const float4 x0 = *(const float4*)(xr);
    const float4 x1 = *(const float4*)(xr + 4);
    float p = dot4(x0, g0) + dot4(x1, g1);
#pragma unroll
    for (int off = 32; off >= 1; off >>= 1) p += __shfl_xor(p, off, 64);
    const float wt = sigm(p);
    fma4(a0, wt, x0); fma4(a1, wt, x1);
  }
  __shared__ __align__(16) float part[4 * 512];
  *(float4*)&part[w * 512 + lane * 8] = a0;
  *(float4*)&part[w * 512 + lane * 8 + 4] = a1;
  __syncthreads();
  float sA = 0.f, sB = 0.f;
#pragma unroll
  for (int w8 = 0; w8 < 4; ++w8) {
    sA += part[w8 * 512 + tid];
    sB += part[w8 * 512 + 256 + tid];
  }
  CTC[(size_t)bid * H_ + tid] = sA;
  CTC[(size_t)bid * H_ + 256 + tid] = sB;
}

// ---------------- K7: online-softmax sweep over contexts ----------------
__global__ __launch_bounds__(256)
void k_sweep_att(const float* __restrict__ ctx, const float* __restrict__ GA,
                 float* __restrict__ CT) {
  const int bid = blockIdx.x, tid = threadIdx.x;
  const int b = bid & 31;
  const int w = tid >> 6, lane = tid & 63;
  const float* gl = GA + (size_t)bid * H_ + lane * 8;
  const float4 g0 = *(const float4*)gl;
  const float4 g1 = *(const float4*)(gl + 4);
  float4 a0 = {0, 0, 0, 0}, a1 = {0, 0, 0, 0};
  float m = -1e30f, l = 0.f;
  const float* base = ctx + (size_t)b * S_ * H_ + lane * 8;
  for (int i = 0; i < 128; ++i) {
    const int s = i * 4 + w;
    const float* xr = base + (size_t)s * H_;
    const float4 x0 = *(const float4*)(xr);
    const float4 x1 = *(const float4*)(xr + 4);
    float p = dot4(x0, g0) + dot4(x1, g1);
#pragma unroll
    for (int off = 32; off >= 1; off >>= 1) p += __shfl_xor(p, off, 64);
    const float m2 = fmaxf(m, p);
    const float f = expf(m - m2);
    const float e = expf(p - m2);
    l = l * f + e;
    scale_fma4(a0, f, e, x0);
    scale_fma4(a1, f, e, x1);
    m = m2;
  }
  __shared__ __align__(16) float part[4 * 512 + 8];
  *(float4*)&part[w * 512 + lane * 8] = a0;
  *(float4*)&part[w * 512 + lane * 8 + 4] = a1;
  if (lane == 0) { part[2048 + w * 2] = m; part[2048 + w * 2 + 1] = l; }
  __syncthreads();
  float M = part[2048];
#pragma unroll
  for (int w8 = 1; w8 < 4; ++w8) M = fmaxf(M, part[2048 + w8 * 2]);
  float fac[4], L = 0.f;
#pragma unroll
  for (int w8 = 0; w8 < 4; ++w8) {
    fac[w8] = expf(part[2048 + w8 * 2] - M);
    L += fac[w8] * part[2048 + w8 * 2 + 1];
  }
  const float inv = 1.0f / L;
  float sA = 0.f, sB = 0.f;
#pragma unroll
  for (int w8 = 0; w8 < 4; ++w8) {
    sA += fac[w8] * part[w8 * 512 + tid];
    sB += fac[w8] * part[w8 * 512 + 256 + tid];
  }
  CT[(size_t)bid * H_ + tid] = sA * inv;
  CT[(size_t)bid * H_ + 256 + tid] = sB * inv;
}

extern "C" void kernel_launch(void* const* d_in, const int* in_sizes, int n_in,
                              void* d_out, int out_size, void* d_ws, size_t ws_size,
                              hipStream_t stream) {
  const int*   inputs  = (const int*)d_in[0];
  const float* h0in    = (const float*)d_in[1];
  const float* c0in    = (const float*)d_in[2];
  const float* ctx     = (const float*)d_in[3];
  const float* ctxc    = (const float*)d_in[4];
  const float* emb     = (const float*)d_in[5];
  const float* W_ih    = (const float*)d_in[6];
  const float* W_hh    = (const float*)d_in[7];
  const float* b_ih    = (const float*)d_in[8];
  const float* b_hh    = (const float*)d_in[9];
  const float* Wi_att  = (const float*)d_in[10];
  const float* bi_att  = (const float*)d_in[11];
  const float* Wo_att  = (const float*)d_in[12];
  const float* bo_att  = (const float*)d_in[13];
  const float* Wi_conv = (const float*)d_in[14];
  const float* bi_conv = (const float*)d_in[15];
  const float* Wo_conv = (const float*)d_in[16];
  const float* bo_conv = (const float*)d_in[17];
  float* out = (float*)d_out;
  float* ws  = (float*)d_ws;

  float* GC  = ws + O_GC;    // gamma_conv, then gamma_att
  float* CTC = ws + O_CTC;   // ct_conv, then ct_att
  float* OCV = ws + O_OCV;   // out_conv

  k_init<<<dim3(256), dim3(512), 0, stream>>>(inputs, h0in, emb, ws);
  k_lstm<<<dim3(LSTM_NWG), dim3(256), 0, stream>>>(W_ih, W_hh, b_ih, b_hh,
                                                   c0in, out, ws);
  // gamma_conv = XH @ Wi_conv^T + bi_conv   (XH stashed in out)
  k_gemm<false, false><<<dim3(512), dim3(256), 0, stream>>>(
      out, nullptr, Wi_conv, bi_conv, nullptr, GC, 0);
  k_sweep_conv<<<dim3(1024), dim3(256), 0, stream>>>(ctxc, GC, CTC);
  // out_conv = tanh([ct_c | XH] @ Wo_conv^T + bo_conv)
  k_gemm<true, false><<<dim3(512), dim3(256), 0, stream>>>(
      CTC, out, Wo_conv, bo_conv, nullptr, OCV, 1);
  // gamma_att = OCV @ Wi_att^T + bi_att
  k_gemm<false, false><<<dim3(512), dim3(256), 0, stream>>>(
      OCV, nullptr, Wi_att, bi_att, nullptr, GC, 0);
  k_sweep_att<<<dim3(1024), dim3(256), 0, stream>>>(ctx, GC, CTC);
  // out = tanh([ct | OCV] @ Wo_att^T + bo_att) + OCV
  k_gemm<true, true><<<dim3(512), dim3(256), 0, stream>>>(
      CTC, OCV, Wo_att, bo_att, OCV, out, 1);
}